// Round 7
// baseline (187.862 us; speedup 1.0000x reference)
//
#include <hip/hip_runtime.h>
#include <cstdio>

#define HID 64
#define D 128            // 2*HID
#define NUM_REL 230
#define NUM_TS 365
#define NCOMB (NUM_REL*NUM_TS)   // 83950
#define SLOPE 0.2f
#define XPAD 136         // LDS row stride in bf16 (272 B -> 2-way bank alias, free)
#define MAXDEG 64        // Poisson(8) max degree ~25; P(deg>=64) < 1e-40

typedef __attribute__((ext_vector_type(8))) short short8;
typedef __attribute__((ext_vector_type(4))) float f32x4;

__device__ __forceinline__ float lrelu(float v){ return v >= 0.f ? v : SLOPE*v; }

// bf16 helpers
__device__ __forceinline__ unsigned bf_rne(float f){
    unsigned u = __float_as_uint(f);
    return (u + 0x7fffu + ((u >> 16) & 1u)) >> 16;
}
__device__ __forceinline__ unsigned pk2(float a, float b){
    return bf_rne(a) | (bf_rne(b) << 16);
}
__device__ __forceinline__ float bf_lo(unsigned u){ return __uint_as_float(u << 16); }
__device__ __forceinline__ float bf_hi(unsigned u){ return __uint_as_float(u & 0xffff0000u); }

// ---------------------------------------------------------------------------
// k_prep: parts (relP/timP) + W-pack ONLY.
// ---------------------------------------------------------------------------
__global__ __launch_bounds__(256) void k_prep(
        const float* __restrict__ rel_table, const float* __restrict__ time_table,
        const float* __restrict__ W_rt, const float* __restrict__ W_fc,
        float* __restrict__ relP, float* __restrict__ timP,
        unsigned short* __restrict__ Wpk13, unsigned short* __restrict__ Wpk2)
{
    int b = blockIdx.x;
    if (b < 298) {
        int row = b*2 + (threadIdx.x >> 7);
        int j   = threadIdx.x & 127;
        if (row >= NUM_REL + NUM_TS) return;
        const float* tbl; const float* Wb; float* out;
        if (row < NUM_REL) { tbl = rel_table + row*HID;            Wb = W_rt;          out = relP + row*D; }
        else               { tbl = time_table + (row-NUM_REL)*HID; Wb = W_rt + HID*D;  out = timP + (row-NUM_REL)*D; }
        float acc = 0.f;
        #pragma unroll
        for (int k = 0; k < HID; ++k) acc += tbl[k] * Wb[k*D + j];
        out[j] = acc;
    } else {
        int id = (b - 298)*256 + threadIdx.x;   // 0..6143
        if (id < 4096) {                 // W13 frags
            int mt = id >> 8;            // 0..15
            int s  = (id >> 6) & 3;
            int l  = id & 63;
            int m  = mt*16 + (l & 15);   // output col 0..255
            int kb = s*32 + (l >> 4)*8;
            unsigned short* dst = Wpk13 + ((size_t)(mt*4 + s)*64 + l)*8;
            #pragma unroll
            for (int j = 0; j < 8; ++j) {
                int k = kb + j;
                float v = (m < D) ? W_fc[(size_t)k*D + m]
                                  : W_fc[(size_t)(256 + k)*D + (m - D)];
                dst[j] = (unsigned short)bf_rne(v);
            }
        } else {                         // W2 frags
            int id2 = id - 4096;
            int mt = id2 >> 8;           // 0..7
            int s  = (id2 >> 6) & 3;
            int l  = id2 & 63;
            int m  = mt*16 + (l & 15);
            int kb = s*32 + (l >> 4)*8;
            unsigned short* dst = Wpk2 + ((size_t)(mt*4 + s)*64 + l)*8;
            #pragma unroll
            for (int j = 0; j < 8; ++j) {
                int k = kb + j;
                dst[j] = (unsigned short)bf_rne(W_fc[(size_t)(D + k)*D + m]);
            }
        }
    }
}

// ---------------------------------------------------------------------------
// k_mm — Bresenham-interleaved scatter (round-5 proven) + rebuilt mm tiles:
//  * A-fragments (Wpk) preloaded into registers ONCE per block, issued before
//    the stage phase so L2 latency hides under staging (round-6 finding: the
//    per-s-iteration af reloads from L2 were the latency binder — MfmaUtil
//    4.8%, VALU 13%, HBM 18%, all idle).
//  * Multi-tile blocks (xw: 2 node-tiles, t2: 4 combo-tiles) amortize the
//    preload and reduce block count 3657 -> 1110.
// ---------------------------------------------------------------------------
__device__ __forceinline__ void xw_body2(
        int xb2, const float* __restrict__ x,
        const unsigned short* __restrict__ Wpk13,
        unsigned short* __restrict__ xW13bf, int n_nodes,
        unsigned short* Xs /* 64*XPAD */)
{
    int t = threadIdx.x;
    int w = t >> 6, l = t & 63;
    int li = l & 15, q = l >> 4;

    // A-frags for this wave's 4 m-tiles, all 4 K-slices: 16 x short8 (64 VGPR)
    short8 af[4][4];   // [s][mi]
    #pragma unroll
    for (int s = 0; s < 4; ++s)
        #pragma unroll
        for (int mi = 0; mi < 4; ++mi)
            af[s][mi] = *(const short8*)(Wpk13 + ((size_t)((w*4 + mi)*4 + s)*64 + l)*8);

    int row = t >> 2;
    int k0  = (t & 3)*32;

    #pragma unroll 1
    for (int r = 0; r < 2; ++r) {
        int nodeBase = (xb2*2 + r)*64;
        {   // stage X tile (fp32 -> bf16), 4 threads per node row
            int node = nodeBase + row;
            unsigned short* dst = Xs + row*XPAD + k0;
            if (node < n_nodes) {
                const float4* src = (const float4*)(x + (size_t)node*D + k0);
                #pragma unroll
                for (int g = 0; g < 8; ++g) {
                    float4 v = src[g];
                    *(uint2*)(dst + g*4) = make_uint2(pk2(v.x, v.y), pk2(v.z, v.w));
                }
            } else {
                #pragma unroll
                for (int g = 0; g < 8; ++g)
                    *(uint2*)(dst + g*4) = make_uint2(0u, 0u);
            }
        }
        __syncthreads();

        f32x4 acc[4][4];
        #pragma unroll
        for (int mi = 0; mi < 4; ++mi)
            #pragma unroll
            for (int ni = 0; ni < 4; ++ni) acc[mi][ni] = (f32x4){0.f,0.f,0.f,0.f};

        #pragma unroll
        for (int s = 0; s < 4; ++s) {
            short8 bf[4];
            #pragma unroll
            for (int ni = 0; ni < 4; ++ni)
                bf[ni] = *(const short8*)(Xs + (ni*16 + li)*XPAD + s*32 + q*8);
            #pragma unroll
            for (int mi = 0; mi < 4; ++mi)
                #pragma unroll
                for (int ni = 0; ni < 4; ++ni)
                    acc[mi][ni] = __builtin_amdgcn_mfma_f32_16x16x32_bf16(
                                      af[s][mi], bf[ni], acc[mi][ni], 0, 0, 0);
        }
        __syncthreads();   // LDS reads done before next r's stage overwrites

        #pragma unroll
        for (int ni = 0; ni < 4; ++ni) {
            int node = nodeBase + ni*16 + li;
            if (node >= n_nodes) continue;
            #pragma unroll
            for (int mi = 0; mi < 4; ++mi) {
                int col = w*64 + mi*16 + q*4;
                *(uint2*)(xW13bf + (size_t)node*256 + col) =
                    make_uint2(pk2(acc[mi][ni][0], acc[mi][ni][1]),
                               pk2(acc[mi][ni][2], acc[mi][ni][3]));
            }
        }
    }
}

__device__ __forceinline__ void t2_body4(
        int tb4, const float* __restrict__ relP, const float* __restrict__ timP,
        const float* __restrict__ b_rt, const unsigned short* __restrict__ Wpk2,
        unsigned short* __restrict__ T2bf,
        unsigned short* Hs /* 64*XPAD */)
{
    int t = threadIdx.x;
    int w = t >> 6, l = t & 63;
    int li = l & 15, q = l >> 4;

    // A-frags: 8 x short8 (32 VGPR)
    short8 af[4][2];   // [s][mi]
    #pragma unroll
    for (int s = 0; s < 4; ++s)
        #pragma unroll
        for (int mi = 0; mi < 2; ++mi)
            af[s][mi] = *(const short8*)(Wpk2 + ((size_t)((w*2 + mi)*4 + s)*64 + l)*8);

    int rrow = t >> 2;
    int hk   = (t & 3)*32;

    #pragma unroll 1
    for (int r = 0; r < 4; ++r) {
        int cBase = (tb4*4 + r)*64;
        {   // stage H tile: lrelu(relP+timP+b) -> bf16, 4 threads per row
            int combo = cBase + rrow;
            if (combo >= NCOMB) combo = NCOMB - 1;
            int rr = combo / NUM_TS;
            int tt = combo - rr*NUM_TS;
            const float4* rv4 = (const float4*)(relP + (size_t)rr*D + hk);
            const float4* tv4 = (const float4*)(timP + (size_t)tt*D + hk);
            const float4* bv4 = (const float4*)(b_rt + hk);
            unsigned short* dst = Hs + rrow*XPAD + hk;
            #pragma unroll
            for (int g = 0; g < 8; ++g) {
                float4 rv = rv4[g], tv = tv4[g], bv = bv4[g];
                float v0 = lrelu(rv.x+tv.x+bv.x), v1 = lrelu(rv.y+tv.y+bv.y);
                float v2 = lrelu(rv.z+tv.z+bv.z), v3 = lrelu(rv.w+tv.w+bv.w);
                *(uint2*)(dst + g*4) = make_uint2(pk2(v0,v1), pk2(v2,v3));
            }
        }
        __syncthreads();

        f32x4 acc[2][4];
        #pragma unroll
        for (int mi = 0; mi < 2; ++mi)
            #pragma unroll
            for (int ni = 0; ni < 4; ++ni) acc[mi][ni] = (f32x4){0.f,0.f,0.f,0.f};

        #pragma unroll
        for (int s = 0; s < 4; ++s) {
            short8 bf[4];
            #pragma unroll
            for (int ni = 0; ni < 4; ++ni)
                bf[ni] = *(const short8*)(Hs + (ni*16 + li)*XPAD + s*32 + q*8);
            #pragma unroll
            for (int mi = 0; mi < 2; ++mi)
                #pragma unroll
                for (int ni = 0; ni < 4; ++ni)
                    acc[mi][ni] = __builtin_amdgcn_mfma_f32_16x16x32_bf16(
                                      af[s][mi], bf[ni], acc[mi][ni], 0, 0, 0);
        }
        __syncthreads();   // LDS reads done before next r's stage overwrites

        #pragma unroll
        for (int ni = 0; ni < 4; ++ni) {
            int combo = cBase + ni*16 + li;
            if (combo >= NCOMB) continue;
            #pragma unroll
            for (int mi = 0; mi < 2; ++mi) {
                int col = (w*2 + mi)*16 + q*4;
                *(uint2*)(T2bf + (size_t)combo*D + col) =
                    make_uint2(pk2(acc[mi][ni][0], acc[mi][ni][1]),
                               pk2(acc[mi][ni][2], acc[mi][ni][3]));
            }
        }
    }
}

__global__ __launch_bounds__(256, 3) void k_mm(
        const float* __restrict__ x, const unsigned short* __restrict__ Wpk13,
        unsigned short* __restrict__ xW13bf, int n_nodes,
        const float* __restrict__ relP, const float* __restrict__ timP,
        const float* __restrict__ b_rt, const unsigned short* __restrict__ Wpk2,
        unsigned short* __restrict__ T2bf,
        const int* __restrict__ edges, int n_edges,
        int* __restrict__ deg, int2* __restrict__ ebuf,
        int nsc, int nxwB, int ntot)
{
    __shared__ __align__(16) unsigned short Hs[64*XPAD];  // 17.4 KB (union)
    int b = blockIdx.x;
    // Bresenham interleave: scatter block iff cumulative count increments.
    int cumCur  = (int)(((long long)b       * nsc) / ntot);
    int cumNext = (int)(((long long)(b + 1) * nsc) / ntot);
    if (cumNext > cumCur) {
        // edge bucket-scatter (4 edges/thread): latency-bound, co-resident
        // with MFMA blocks. deg zeroed by hipMemsetAsync blit (round-3
        // lesson: plain-store zeroing -> stale memory-side atomics).
        int e0 = (cumCur*256 + threadIdx.x)*4;
        const int4* ep = (const int4*)edges;
        if (e0 + 3 < n_edges) {
            int4 a = ep[e0+0];
            int4 bb = ep[e0+1];
            int4 c = ep[e0+2];
            int4 d = ep[e0+3];
            int sa = atomicAdd(&deg[a.y], 1);
            int sb = atomicAdd(&deg[bb.y], 1);
            int sc = atomicAdd(&deg[c.y], 1);
            int sd = atomicAdd(&deg[d.y], 1);
            if (sa < MAXDEG) ebuf[(size_t)a.y*MAXDEG + sa] = make_int2(a.x, a.z*NUM_TS + a.w);
            if (sb < MAXDEG) ebuf[(size_t)bb.y*MAXDEG + sb] = make_int2(bb.x, bb.z*NUM_TS + bb.w);
            if (sc < MAXDEG) ebuf[(size_t)c.y*MAXDEG + sc] = make_int2(c.x, c.z*NUM_TS + c.w);
            if (sd < MAXDEG) ebuf[(size_t)d.y*MAXDEG + sd] = make_int2(d.x, d.z*NUM_TS + d.w);
        } else {
            for (int e = e0; e < n_edges; ++e) {
                int4 ed = ep[e];
                int slot = atomicAdd(&deg[ed.y], 1);
                if (slot < MAXDEG)
                    ebuf[(size_t)ed.y*MAXDEG + slot] = make_int2(ed.x, ed.z*NUM_TS + ed.w);
            }
        }
    } else {
        int cidx = b - cumNext;
        if (cidx < nxwB) {
            xw_body2(cidx, x, Wpk13, xW13bf, n_nodes, Hs);
        } else {
            t2_body4(cidx - nxwB, relP, timP, b_rt, Wpk2, T2bf, Hs);
        }
    }
}

// ---------------------------------------------------------------------------
// k_agg: 4 nodes per wave, 16 lanes per node, uint4 (16B) gathers.
// (unchanged — measured at the random-gather path floor ~42 µs)
// ---------------------------------------------------------------------------
__global__ __launch_bounds__(256) void k_agg(
        const int* __restrict__ deg, const int2* __restrict__ ebuf,
        const unsigned short* __restrict__ xW13bf,
        const unsigned short* __restrict__ T2bf,
        const float* __restrict__ b_fc,
        float* __restrict__ out, int n_nodes)
{
    int t    = threadIdx.x;
    int lane = t & 63;
    int g    = lane >> 4;             // node group within wave (0..3)
    int sub  = lane & 15;             // lane within group; covers cols sub*8..+7
    int node = blockIdx.x*16 + (t >> 6)*4 + g;
    bool valid = node < n_nodes;
    int nodeC  = valid ? node : n_nodes - 1;

    int dg  = deg[nodeC];
    int cnt = valid ? (dg < MAXDEG ? dg : MAXDEG) : 0;
    int cm1 = cnt > 0 ? cnt - 1 : 0;
    const int2* eb = ebuf + (size_t)nodeC * MAXDEG;

    // wave-max trip count (cnt is uniform within each 16-lane group)
    int cmax = cnt;
    cmax = max(cmax, __shfl_xor(cmax, 16));
    cmax = max(cmax, __shfl_xor(cmax, 32));

    // base = xW3[node] + b_fc for this lane's 8 cols
    float base[8];
    {
        uint4  w3  = *(const uint4*)&xW13bf[(size_t)nodeC*256 + 128 + sub*8];
        float4 blo = *(const float4*)&b_fc[sub*8];
        float4 bhi = *(const float4*)&b_fc[sub*8 + 4];
        base[0] = bf_lo(w3.x) + blo.x; base[1] = bf_hi(w3.x) + blo.y;
        base[2] = bf_lo(w3.y) + blo.z; base[3] = bf_hi(w3.y) + blo.w;
        base[4] = bf_lo(w3.z) + bhi.x; base[5] = bf_hi(w3.z) + bhi.y;
        base[6] = bf_lo(w3.w) + bhi.z; base[7] = bf_hi(w3.w) + bhi.w;
    }

    float acc[8];
    #pragma unroll
    for (int k = 0; k < 8; ++k) acc[k] = 0.f;

    const unsigned sMax = (unsigned)(n_nodes - 1);
    const unsigned cMax = (unsigned)(NCOMB - 1);

    for (int e = 0; e < cmax; e += 4) {
        // --- batch 1: index loads (independent, clamped in-bounds) ---
        int2 e0 = eb[min(e + 0, cm1)];
        int2 e1 = eb[min(e + 1, cm1)];
        int2 e2 = eb[min(e + 2, cm1)];
        int2 e3 = eb[min(e + 3, cm1)];
        // --- clamp gather targets (garbage-safe for masked slots) ---
        unsigned s0 = min((unsigned)e0.x, sMax), c0 = min((unsigned)e0.y, cMax);
        unsigned s1 = min((unsigned)e1.x, sMax), c1 = min((unsigned)e1.y, cMax);
        unsigned s2 = min((unsigned)e2.x, sMax), c2 = min((unsigned)e2.y, cMax);
        unsigned s3 = min((unsigned)e3.x, sMax), c3 = min((unsigned)e3.y, cMax);
        // --- batch 2: 8 independent 16B gathers ---
        uint4 S0 = *(const uint4*)&xW13bf[(size_t)s0*256 + sub*8];
        uint4 T0 = *(const uint4*)&T2bf  [(size_t)c0*D   + sub*8];
        uint4 S1 = *(const uint4*)&xW13bf[(size_t)s1*256 + sub*8];
        uint4 T1 = *(const uint4*)&T2bf  [(size_t)c1*D   + sub*8];
        uint4 S2 = *(const uint4*)&xW13bf[(size_t)s2*256 + sub*8];
        uint4 T2 = *(const uint4*)&T2bf  [(size_t)c2*D   + sub*8];
        uint4 S3 = *(const uint4*)&xW13bf[(size_t)s3*256 + sub*8];
        uint4 T3 = *(const uint4*)&T2bf  [(size_t)c3*D   + sub*8];
        // --- consume (cndmask-masked; no divergent control flow) ---
        bool m0 = (e + 0) < cnt, m1 = (e + 1) < cnt;
        bool m2 = (e + 2) < cnt, m3 = (e + 3) < cnt;
        #pragma unroll
        for (int w = 0; w < 4; ++w) {
            unsigned Sw0 = (&S0.x)[w], Tw0 = (&T0.x)[w];
            unsigned Sw1 = (&S1.x)[w], Tw1 = (&T1.x)[w];
            unsigned Sw2 = (&S2.x)[w], Tw2 = (&T2.x)[w];
            unsigned Sw3 = (&S3.x)[w], Tw3 = (&T3.x)[w];
            float v0l = lrelu(bf_lo(Sw0) + bf_lo(Tw0) + base[2*w]);
            float v0h = lrelu(bf_hi(Sw0) + bf_hi(Tw0) + base[2*w+1]);
            float v1l = lrelu(bf_lo(Sw1) + bf_lo(Tw1) + base[2*w]);
            float v1h = lrelu(bf_hi(Sw1) + bf_hi(Tw1) + base[2*w+1]);
            float v2l = lrelu(bf_lo(Sw2) + bf_lo(Tw2) + base[2*w]);
            float v2h = lrelu(bf_hi(Sw2) + bf_hi(Tw2) + base[2*w+1]);
            float v3l = lrelu(bf_lo(Sw3) + bf_lo(Tw3) + base[2*w]);
            float v3h = lrelu(bf_hi(Sw3) + bf_hi(Tw3) + base[2*w+1]);
            float a01l = (m0 ? v0l : 0.f) + (m1 ? v1l : 0.f);
            float a23l = (m2 ? v2l : 0.f) + (m3 ? v3l : 0.f);
            float a01h = (m0 ? v0h : 0.f) + (m1 ? v1h : 0.f);
            float a23h = (m2 ? v2h : 0.f) + (m3 ? v3h : 0.f);
            acc[2*w]   += a01l + a23l;
            acc[2*w+1] += a01h + a23h;
        }
    }

    if (!valid) return;
    float inv = 1.f / fmaxf((float)dg, 1.f);
    float4 o0 = make_float4(acc[0]*inv, acc[1]*inv, acc[2]*inv, acc[3]*inv);
    float4 o1 = make_float4(acc[4]*inv, acc[5]*inv, acc[6]*inv, acc[7]*inv);
    *(float4*)&out[(size_t)node*D + sub*8]     = o0;
    *(float4*)&out[(size_t)node*D + sub*8 + 4] = o1;
}

// ---------------------------------------------------------------------------
extern "C" void kernel_launch(void* const* d_in, const int* in_sizes, int n_in,
                              void* d_out, int out_size, void* d_ws, size_t ws_size,
                              hipStream_t stream)
{
    const float* x          = (const float*)d_in[0];
    const float* rel_table  = (const float*)d_in[1];
    const float* time_table = (const float*)d_in[2];
    const float* W_rt       = (const float*)d_in[3];
    const float* b_rt       = (const float*)d_in[4];
    const float* W_fc       = (const float*)d_in[5];
    const float* b_fc       = (const float*)d_in[6];
    const int*   edges      = (const int*)d_in[7];

    int n_nodes = in_sizes[0] / D;   // 50000
    int n_edges = in_sizes[7] / 4;   // 400000
    int nsc     = (n_edges/4 + 255) / 256;       // 391 scatter blocks (4 e/thr)
    int nxwB    = ((n_nodes + 63)/64 + 1) / 2;   // 391 xw blocks (2 tiles each)
    int nt2B    = ((NCOMB + 63)/64 + 3) / 4;     // 328 t2 blocks (4 tiles each)
    int ntot    = nsc + nxwB + nt2B;             // 1110

    char* ws = (char*)d_ws;
    size_t off = 0;
    auto alloc = [&](size_t bytes) -> void* {
        void* p = ws + off; off += (bytes + 255) & ~(size_t)255; return p;
    };
    unsigned short* xW13bf = (unsigned short*)alloc((size_t)n_nodes * 256 * 2); // 25.6 MB
    unsigned short* T2bf   = (unsigned short*)alloc((size_t)NCOMB * D * 2);     // 21.5 MB
    unsigned short* Wpk13  = (unsigned short*)alloc((size_t)16*4*64*8 * 2);     // 64 KB
    unsigned short* Wpk2   = (unsigned short*)alloc((size_t)8*4*64*8 * 2);      // 32 KB
    float* relP   = (float*)alloc((size_t)NUM_REL * D * sizeof(float));
    float* timP   = (float*)alloc((size_t)NUM_TS * D * sizeof(float));
    int*   deg    = (int*)alloc((size_t)n_nodes * sizeof(int));
    int2*  ebuf   = (int2*)alloc((size_t)n_nodes * MAXDEG * sizeof(int2));      // 25.6 MB
    if (off > ws_size)
        fprintf(stderr, "kernel_launch: workspace too small: need %zu, have %zu\n", off, ws_size);

    hipMemsetAsync(deg, 0, (size_t)n_nodes * sizeof(int), stream);

    k_prep<<<322, 256, 0, stream>>>(rel_table, time_table, W_rt, W_fc,
                                    relP, timP, Wpk13, Wpk2);
    k_mm  <<<ntot, 256, 0, stream>>>(x, Wpk13, xW13bf, n_nodes,
                                     relP, timP, b_rt, Wpk2, T2bf,
                                     edges, n_edges, deg, ebuf,
                                     nsc, nxwB, ntot);
    k_agg <<<(n_nodes + 15)/16, 256, 0, stream>>>(deg, ebuf, xW13bf, T2bf,
                                                  b_fc, (float*)d_out, n_nodes);
}

// Round 8
// 183.615 us; speedup vs baseline: 1.0231x; 1.0231x over previous
//
#include <hip/hip_runtime.h>
#include <cstdio>

#define HID 64
#define D 128            // 2*HID
#define NUM_REL 230
#define NUM_TS 365
#define NCOMB (NUM_REL*NUM_TS)   // 83950
#define SLOPE 0.2f
#define XPAD 136         // LDS row stride in bf16 (272 B -> 2-way bank alias, free)
#define MAXDEG 64        // Poisson(8) max degree ~25; P(deg>=64) < 1e-40

typedef __attribute__((ext_vector_type(8))) short short8;
typedef __attribute__((ext_vector_type(4))) float f32x4;

__device__ __forceinline__ float lrelu(float v){ return v >= 0.f ? v : SLOPE*v; }

// bf16 helpers
__device__ __forceinline__ unsigned bf_rne(float f){
    unsigned u = __float_as_uint(f);
    return (u + 0x7fffu + ((u >> 16) & 1u)) >> 16;
}
__device__ __forceinline__ unsigned pk2(float a, float b){
    return bf_rne(a) | (bf_rne(b) << 16);
}
__device__ __forceinline__ float bf_lo(unsigned u){ return __uint_as_float(u << 16); }
__device__ __forceinline__ float bf_hi(unsigned u){ return __uint_as_float(u & 0xffff0000u); }

// ---------------------------------------------------------------------------
// k_ps — prep + scatter MERGED (round-8): both are latency-bound preludes
// with disjoint data and different stressed resources (L2 loads/VALU vs
// atomics), so co-residency overlaps them; also deletes one launch gap.
// blocks [0,nsc)        : edge bucket-scatter, 4 edges/thread
// blocks [nsc,nsc+298)  : relP/timP rows (2 rows per block)
// blocks [nsc+298,+322) : pack W13^T / W2^T into MFMA A-frag order (bf16)
// deg zeroed by hipMemsetAsync blit (round-3 lesson: plain-store zeroing ->
// stale memory-side atomics on non-coherent per-XCD L2).
// ---------------------------------------------------------------------------
__global__ __launch_bounds__(256) void k_ps(
        const float* __restrict__ rel_table, const float* __restrict__ time_table,
        const float* __restrict__ W_rt, const float* __restrict__ W_fc,
        float* __restrict__ relP, float* __restrict__ timP,
        unsigned short* __restrict__ Wpk13, unsigned short* __restrict__ Wpk2,
        const int* __restrict__ edges, int n_edges,
        int* __restrict__ deg, int2* __restrict__ ebuf, int nsc)
{
    int blk = blockIdx.x;
    if (blk < nsc) {
        // ---- edge bucket-scatter: 4 edges/thread, straight-line ----
        int e0 = (blk*256 + threadIdx.x)*4;
        const int4* ep = (const int4*)edges;
        if (e0 + 3 < n_edges) {
            int4 a = ep[e0+0];
            int4 b = ep[e0+1];
            int4 c = ep[e0+2];
            int4 d = ep[e0+3];
            int sa = atomicAdd(&deg[a.y], 1);
            int sb = atomicAdd(&deg[b.y], 1);
            int sc = atomicAdd(&deg[c.y], 1);
            int sd = atomicAdd(&deg[d.y], 1);
            if (sa < MAXDEG) ebuf[(size_t)a.y*MAXDEG + sa] = make_int2(a.x, a.z*NUM_TS + a.w);
            if (sb < MAXDEG) ebuf[(size_t)b.y*MAXDEG + sb] = make_int2(b.x, b.z*NUM_TS + b.w);
            if (sc < MAXDEG) ebuf[(size_t)c.y*MAXDEG + sc] = make_int2(c.x, c.z*NUM_TS + c.w);
            if (sd < MAXDEG) ebuf[(size_t)d.y*MAXDEG + sd] = make_int2(d.x, d.z*NUM_TS + d.w);
        } else {
            for (int e = e0; e < n_edges; ++e) {
                int4 ed = ep[e];
                int slot = atomicAdd(&deg[ed.y], 1);
                if (slot < MAXDEG)
                    ebuf[(size_t)ed.y*MAXDEG + slot] = make_int2(ed.x, ed.z*NUM_TS + ed.w);
            }
        }
        return;
    }
    int b = blk - nsc;
    if (b < 298) {
        int row = b*2 + (threadIdx.x >> 7);
        int j   = threadIdx.x & 127;
        if (row >= NUM_REL + NUM_TS) return;
        const float* tbl; const float* Wb; float* out;
        if (row < NUM_REL) { tbl = rel_table + row*HID;            Wb = W_rt;          out = relP + row*D; }
        else               { tbl = time_table + (row-NUM_REL)*HID; Wb = W_rt + HID*D;  out = timP + (row-NUM_REL)*D; }
        float acc = 0.f;
        #pragma unroll
        for (int k = 0; k < HID; ++k) acc += tbl[k] * Wb[k*D + j];
        out[j] = acc;
    } else {
        int id = (b - 298)*256 + threadIdx.x;   // 0..6143
        if (id < 4096) {                 // W13 frags
            int mt = id >> 8;            // 0..15
            int s  = (id >> 6) & 3;
            int l  = id & 63;
            int m  = mt*16 + (l & 15);   // output col 0..255
            int kb = s*32 + (l >> 4)*8;
            unsigned short* dst = Wpk13 + ((size_t)(mt*4 + s)*64 + l)*8;
            #pragma unroll
            for (int j = 0; j < 8; ++j) {
                int k = kb + j;
                float v = (m < D) ? W_fc[(size_t)k*D + m]
                                  : W_fc[(size_t)(256 + k)*D + (m - D)];
                dst[j] = (unsigned short)bf_rne(v);
            }
        } else {                         // W2 frags
            int id2 = id - 4096;
            int mt = id2 >> 8;           // 0..7
            int s  = (id2 >> 6) & 3;
            int l  = id2 & 63;
            int m  = mt*16 + (l & 15);
            int kb = s*32 + (l >> 4)*8;
            unsigned short* dst = Wpk2 + ((size_t)(mt*4 + s)*64 + l)*8;
            #pragma unroll
            for (int j = 0; j < 8; ++j) {
                int k = kb + j;
                dst[j] = (unsigned short)bf_rne(W_fc[(size_t)(D + k)*D + m]);
            }
        }
    }
}

// ---------------------------------------------------------------------------
// k_mm — round-6 PURE form reproduced exactly (measured 42 µs, VGPR 52 —
// stays under the 64-VGPR wave-capacity cliff that killed round-7's preload).
// xw: 64-node tiles; t2: 64-combo tiles; Hs = 64*XPAD (17.4 KB union).
// ---------------------------------------------------------------------------
__device__ __forceinline__ void xw_body(
        int xb, const float* __restrict__ x,
        const unsigned short* __restrict__ Wpk13,
        unsigned short* __restrict__ xW13bf, int n_nodes,
        unsigned short* Xs /* 64*XPAD */)
{
    int t = threadIdx.x;
    int nodeBase = xb*64;
    {   // stage X tile (fp32 -> bf16), 4 threads per node row
        int row = t >> 2;
        int k0  = (t & 3)*32;
        int node = nodeBase + row;
        unsigned short* dst = Xs + row*XPAD + k0;
        if (node < n_nodes) {
            const float4* src = (const float4*)(x + (size_t)node*D + k0);
            #pragma unroll
            for (int g = 0; g < 8; ++g) {
                float4 v = src[g];
                *(uint2*)(dst + g*4) = make_uint2(pk2(v.x, v.y), pk2(v.z, v.w));
            }
        } else {
            #pragma unroll
            for (int g = 0; g < 8; ++g)
                *(uint2*)(dst + g*4) = make_uint2(0u, 0u);
        }
    }
    __syncthreads();

    int w = t >> 6, l = t & 63;
    int li = l & 15, q = l >> 4;

    f32x4 acc[4][4];
    #pragma unroll
    for (int mi = 0; mi < 4; ++mi)
        #pragma unroll
        for (int ni = 0; ni < 4; ++ni) acc[mi][ni] = (f32x4){0.f,0.f,0.f,0.f};

    #pragma unroll 1
    for (int s = 0; s < 4; ++s) {
        short8 af[4], bf[4];
        #pragma unroll
        for (int mi = 0; mi < 4; ++mi) {
            int mt = w*4 + mi;
            af[mi] = *(const short8*)(Wpk13 + ((size_t)(mt*4 + s)*64 + l)*8);
        }
        #pragma unroll
        for (int ni = 0; ni < 4; ++ni)
            bf[ni] = *(const short8*)(Xs + (ni*16 + li)*XPAD + s*32 + q*8);
        #pragma unroll
        for (int mi = 0; mi < 4; ++mi)
            #pragma unroll
            for (int ni = 0; ni < 4; ++ni)
                acc[mi][ni] = __builtin_amdgcn_mfma_f32_16x16x32_bf16(
                                  af[mi], bf[ni], acc[mi][ni], 0, 0, 0);
    }
    #pragma unroll
    for (int ni = 0; ni < 4; ++ni) {
        int node = nodeBase + ni*16 + li;
        if (node >= n_nodes) continue;
        #pragma unroll
        for (int mi = 0; mi < 4; ++mi) {
            int col = w*64 + mi*16 + q*4;
            *(uint2*)(xW13bf + (size_t)node*256 + col) =
                make_uint2(pk2(acc[mi][ni][0], acc[mi][ni][1]),
                           pk2(acc[mi][ni][2], acc[mi][ni][3]));
        }
    }
}

__device__ __forceinline__ void t2_body(
        int tb, const float* __restrict__ relP, const float* __restrict__ timP,
        const float* __restrict__ b_rt, const unsigned short* __restrict__ Wpk2,
        unsigned short* __restrict__ T2bf,
        unsigned short* Hs /* 64*XPAD */)
{
    int t = threadIdx.x;
    int cBase = tb*64;
    {   // stage H tile: lrelu(relP+timP+b) -> bf16, 4 threads per row
        int r  = t >> 2;
        int hk = (t & 3)*32;
        int combo = cBase + r;
        if (combo >= NCOMB) combo = NCOMB - 1;
        int rr = combo / NUM_TS;
        int tt = combo - rr*NUM_TS;
        const float4* rv4 = (const float4*)(relP + (size_t)rr*D + hk);
        const float4* tv4 = (const float4*)(timP + (size_t)tt*D + hk);
        const float4* bv4 = (const float4*)(b_rt + hk);
        unsigned short* dst = Hs + r*XPAD + hk;
        #pragma unroll
        for (int g = 0; g < 8; ++g) {
            float4 rv = rv4[g], tv = tv4[g], bv = bv4[g];
            float v0 = lrelu(rv.x+tv.x+bv.x), v1 = lrelu(rv.y+tv.y+bv.y);
            float v2 = lrelu(rv.z+tv.z+bv.z), v3 = lrelu(rv.w+tv.w+bv.w);
            *(uint2*)(dst + g*4) = make_uint2(pk2(v0,v1), pk2(v2,v3));
        }
    }
    __syncthreads();

    int w = t >> 6, l = t & 63;
    int li = l & 15, q = l >> 4;

    f32x4 acc[2][4];
    #pragma unroll
    for (int mi = 0; mi < 2; ++mi)
        #pragma unroll
        for (int ni = 0; ni < 4; ++ni) acc[mi][ni] = (f32x4){0.f,0.f,0.f,0.f};

    #pragma unroll 1
    for (int s = 0; s < 4; ++s) {
        short8 af[2], bf[4];
        #pragma unroll
        for (int mi = 0; mi < 2; ++mi) {
            int mt = w*2 + mi;
            af[mi] = *(const short8*)(Wpk2 + ((size_t)(mt*4 + s)*64 + l)*8);
        }
        #pragma unroll
        for (int ni = 0; ni < 4; ++ni)
            bf[ni] = *(const short8*)(Hs + (ni*16 + li)*XPAD + s*32 + q*8);
        #pragma unroll
        for (int mi = 0; mi < 2; ++mi)
            #pragma unroll
            for (int ni = 0; ni < 4; ++ni)
                acc[mi][ni] = __builtin_amdgcn_mfma_f32_16x16x32_bf16(
                                  af[mi], bf[ni], acc[mi][ni], 0, 0, 0);
    }
    #pragma unroll
    for (int ni = 0; ni < 4; ++ni) {
        int combo = cBase + ni*16 + li;
        if (combo >= NCOMB) continue;
        #pragma unroll
        for (int mi = 0; mi < 2; ++mi) {
            int col = (w*2 + mi)*16 + q*4;
            *(uint2*)(T2bf + (size_t)combo*D + col) =
                make_uint2(pk2(acc[mi][ni][0], acc[mi][ni][1]),
                           pk2(acc[mi][ni][2], acc[mi][ni][3]));
        }
    }
}

__global__ __launch_bounds__(256, 3) void k_mm(
        const float* __restrict__ x, const unsigned short* __restrict__ Wpk13,
        unsigned short* __restrict__ xW13bf, int n_nodes,
        const float* __restrict__ relP, const float* __restrict__ timP,
        const float* __restrict__ b_rt, const unsigned short* __restrict__ Wpk2,
        unsigned short* __restrict__ T2bf, int nxw)
{
    __shared__ __align__(16) unsigned short Hs[64*XPAD];  // 17.4 KB (union)
    int b = blockIdx.x;
    if (b < nxw) {
        xw_body(b, x, Wpk13, xW13bf, n_nodes, Hs);
    } else {
        t2_body(b - nxw, relP, timP, b_rt, Wpk2, T2bf, Hs);
    }
}

// ---------------------------------------------------------------------------
// k_agg: 4 nodes per wave, 16 lanes per node, uint4 (16B) gathers.
// (unchanged — at the L3 random-gather BW floor: ~205 MB at ~5 TB/s)
// ---------------------------------------------------------------------------
__global__ __launch_bounds__(256) void k_agg(
        const int* __restrict__ deg, const int2* __restrict__ ebuf,
        const unsigned short* __restrict__ xW13bf,
        const unsigned short* __restrict__ T2bf,
        const float* __restrict__ b_fc,
        float* __restrict__ out, int n_nodes)
{
    int t    = threadIdx.x;
    int lane = t & 63;
    int g    = lane >> 4;             // node group within wave (0..3)
    int sub  = lane & 15;             // lane within group; covers cols sub*8..+7
    int node = blockIdx.x*16 + (t >> 6)*4 + g;
    bool valid = node < n_nodes;
    int nodeC  = valid ? node : n_nodes - 1;

    int dg  = deg[nodeC];
    int cnt = valid ? (dg < MAXDEG ? dg : MAXDEG) : 0;
    int cm1 = cnt > 0 ? cnt - 1 : 0;
    const int2* eb = ebuf + (size_t)nodeC * MAXDEG;

    // wave-max trip count (cnt is uniform within each 16-lane group)
    int cmax = cnt;
    cmax = max(cmax, __shfl_xor(cmax, 16));
    cmax = max(cmax, __shfl_xor(cmax, 32));

    // base = xW3[node] + b_fc for this lane's 8 cols
    float base[8];
    {
        uint4  w3  = *(const uint4*)&xW13bf[(size_t)nodeC*256 + 128 + sub*8];
        float4 blo = *(const float4*)&b_fc[sub*8];
        float4 bhi = *(const float4*)&b_fc[sub*8 + 4];
        base[0] = bf_lo(w3.x) + blo.x; base[1] = bf_hi(w3.x) + blo.y;
        base[2] = bf_lo(w3.y) + blo.z; base[3] = bf_hi(w3.y) + blo.w;
        base[4] = bf_lo(w3.z) + bhi.x; base[5] = bf_hi(w3.z) + bhi.y;
        base[6] = bf_lo(w3.w) + bhi.z; base[7] = bf_hi(w3.w) + bhi.w;
    }

    float acc[8];
    #pragma unroll
    for (int k = 0; k < 8; ++k) acc[k] = 0.f;

    const unsigned sMax = (unsigned)(n_nodes - 1);
    const unsigned cMax = (unsigned)(NCOMB - 1);

    for (int e = 0; e < cmax; e += 4) {
        // --- batch 1: index loads (independent, clamped in-bounds) ---
        int2 e0 = eb[min(e + 0, cm1)];
        int2 e1 = eb[min(e + 1, cm1)];
        int2 e2 = eb[min(e + 2, cm1)];
        int2 e3 = eb[min(e + 3, cm1)];
        // --- clamp gather targets (garbage-safe for masked slots) ---
        unsigned s0 = min((unsigned)e0.x, sMax), c0 = min((unsigned)e0.y, cMax);
        unsigned s1 = min((unsigned)e1.x, sMax), c1 = min((unsigned)e1.y, cMax);
        unsigned s2 = min((unsigned)e2.x, sMax), c2 = min((unsigned)e2.y, cMax);
        unsigned s3 = min((unsigned)e3.x, sMax), c3 = min((unsigned)e3.y, cMax);
        // --- batch 2: 8 independent 16B gathers ---
        uint4 S0 = *(const uint4*)&xW13bf[(size_t)s0*256 + sub*8];
        uint4 T0 = *(const uint4*)&T2bf  [(size_t)c0*D   + sub*8];
        uint4 S1 = *(const uint4*)&xW13bf[(size_t)s1*256 + sub*8];
        uint4 T1 = *(const uint4*)&T2bf  [(size_t)c1*D   + sub*8];
        uint4 S2 = *(const uint4*)&xW13bf[(size_t)s2*256 + sub*8];
        uint4 T2 = *(const uint4*)&T2bf  [(size_t)c2*D   + sub*8];
        uint4 S3 = *(const uint4*)&xW13bf[(size_t)s3*256 + sub*8];
        uint4 T3 = *(const uint4*)&T2bf  [(size_t)c3*D   + sub*8];
        // --- consume (cndmask-masked; no divergent control flow) ---
        bool m0 = (e + 0) < cnt, m1 = (e + 1) < cnt;
        bool m2 = (e + 2) < cnt, m3 = (e + 3) < cnt;
        #pragma unroll
        for (int w = 0; w < 4; ++w) {
            unsigned Sw0 = (&S0.x)[w], Tw0 = (&T0.x)[w];
            unsigned Sw1 = (&S1.x)[w], Tw1 = (&T1.x)[w];
            unsigned Sw2 = (&S2.x)[w], Tw2 = (&T2.x)[w];
            unsigned Sw3 = (&S3.x)[w], Tw3 = (&T3.x)[w];
            float v0l = lrelu(bf_lo(Sw0) + bf_lo(Tw0) + base[2*w]);
            float v0h = lrelu(bf_hi(Sw0) + bf_hi(Tw0) + base[2*w+1]);
            float v1l = lrelu(bf_lo(Sw1) + bf_lo(Tw1) + base[2*w]);
            float v1h = lrelu(bf_hi(Sw1) + bf_hi(Tw1) + base[2*w+1]);
            float v2l = lrelu(bf_lo(Sw2) + bf_lo(Tw2) + base[2*w]);
            float v2h = lrelu(bf_hi(Sw2) + bf_hi(Tw2) + base[2*w+1]);
            float v3l = lrelu(bf_lo(Sw3) + bf_lo(Tw3) + base[2*w]);
            float v3h = lrelu(bf_hi(Sw3) + bf_hi(Tw3) + base[2*w+1]);
            float a01l = (m0 ? v0l : 0.f) + (m1 ? v1l : 0.f);
            float a23l = (m2 ? v2l : 0.f) + (m3 ? v3l : 0.f);
            float a01h = (m0 ? v0h : 0.f) + (m1 ? v1h : 0.f);
            float a23h = (m2 ? v2h : 0.f) + (m3 ? v3h : 0.f);
            acc[2*w]   += a01l + a23l;
            acc[2*w+1] += a01h + a23h;
        }
    }

    if (!valid) return;
    float inv = 1.f / fmaxf((float)dg, 1.f);
    float4 o0 = make_float4(acc[0]*inv, acc[1]*inv, acc[2]*inv, acc[3]*inv);
    float4 o1 = make_float4(acc[4]*inv, acc[5]*inv, acc[6]*inv, acc[7]*inv);
    *(float4*)&out[(size_t)node*D + sub*8]     = o0;
    *(float4*)&out[(size_t)node*D + sub*8 + 4] = o1;
}

// ---------------------------------------------------------------------------
extern "C" void kernel_launch(void* const* d_in, const int* in_sizes, int n_in,
                              void* d_out, int out_size, void* d_ws, size_t ws_size,
                              hipStream_t stream)
{
    const float* x          = (const float*)d_in[0];
    const float* rel_table  = (const float*)d_in[1];
    const float* time_table = (const float*)d_in[2];
    const float* W_rt       = (const float*)d_in[3];
    const float* b_rt       = (const float*)d_in[4];
    const float* W_fc       = (const float*)d_in[5];
    const float* b_fc       = (const float*)d_in[6];
    const int*   edges      = (const int*)d_in[7];

    int n_nodes = in_sizes[0] / D;   // 50000
    int n_edges = in_sizes[7] / 4;   // 400000
    int nsc     = (n_edges/4 + 255) / 256;  // 391 scatter blocks (4 e/thr)
    int nxw     = (n_nodes + 63) / 64;      // 782
    int nt2     = (NCOMB + 63) / 64;        // 1312

    char* ws = (char*)d_ws;
    size_t off = 0;
    auto alloc = [&](size_t bytes) -> void* {
        void* p = ws + off; off += (bytes + 255) & ~(size_t)255; return p;
    };
    unsigned short* xW13bf = (unsigned short*)alloc((size_t)n_nodes * 256 * 2); // 25.6 MB
    unsigned short* T2bf   = (unsigned short*)alloc((size_t)NCOMB * D * 2);     // 21.5 MB
    unsigned short* Wpk13  = (unsigned short*)alloc((size_t)16*4*64*8 * 2);     // 64 KB
    unsigned short* Wpk2   = (unsigned short*)alloc((size_t)8*4*64*8 * 2);      // 32 KB
    float* relP   = (float*)alloc((size_t)NUM_REL * D * sizeof(float));
    float* timP   = (float*)alloc((size_t)NUM_TS * D * sizeof(float));
    int*   deg    = (int*)alloc((size_t)n_nodes * sizeof(int));
    int2*  ebuf   = (int2*)alloc((size_t)n_nodes * MAXDEG * sizeof(int2));      // 25.6 MB
    if (off > ws_size)
        fprintf(stderr, "kernel_launch: workspace too small: need %zu, have %zu\n", off, ws_size);

    hipMemsetAsync(deg, 0, (size_t)n_nodes * sizeof(int), stream);

    k_ps <<<nsc + 322, 256, 0, stream>>>(rel_table, time_table, W_rt, W_fc,
                                         relP, timP, Wpk13, Wpk2,
                                         edges, n_edges, deg, ebuf, nsc);
    k_mm <<<nxw + nt2, 256, 0, stream>>>(x, Wpk13, xW13bf, n_nodes,
                                         relP, timP, b_rt, Wpk2, T2bf, nxw);
    k_agg<<<(n_nodes + 15)/16, 256, 0, stream>>>(deg, ebuf, xW13bf, T2bf,
                                                 b_fc, (float*)d_out, n_nodes);
}

// Round 9
// 171.011 us; speedup vs baseline: 1.0985x; 1.0737x over previous
//
#include <hip/hip_runtime.h>
#include <cstdio>

#define HID 64
#define D 128            // 2*HID
#define NUM_REL 230
#define NUM_TS 365
#define NCOMB (NUM_REL*NUM_TS)   // 83950
#define SLOPE 0.2f
#define XPAD 136         // LDS row stride in bf16 (272 B -> 2-way bank alias, free)
#define MAXDEG 64        // Poisson(8) max degree ~25; P(deg>=64) < 1e-40

typedef __attribute__((ext_vector_type(8))) short short8;
typedef __attribute__((ext_vector_type(4))) float f32x4;

__device__ __forceinline__ float lrelu(float v){ return v >= 0.f ? v : SLOPE*v; }

// bf16 helpers
__device__ __forceinline__ unsigned bf_rne(float f){
    unsigned u = __float_as_uint(f);
    return (u + 0x7fffu + ((u >> 16) & 1u)) >> 16;
}
__device__ __forceinline__ unsigned pk2(float a, float b){
    return bf_rne(a) | (bf_rne(b) << 16);
}
__device__ __forceinline__ float bf_lo(unsigned u){ return __uint_as_float(u << 16); }
__device__ __forceinline__ float bf_hi(unsigned u){ return __uint_as_float(u & 0xffff0000u); }

// ---------------------------------------------------------------------------
// k_prep: parts (relP/timP) + W-pack ONLY.  (round-5 form, measured ~12 µs)
// ---------------------------------------------------------------------------
__global__ __launch_bounds__(256) void k_prep(
        const float* __restrict__ rel_table, const float* __restrict__ time_table,
        const float* __restrict__ W_rt, const float* __restrict__ W_fc,
        float* __restrict__ relP, float* __restrict__ timP,
        unsigned short* __restrict__ Wpk13, unsigned short* __restrict__ Wpk2)
{
    int b = blockIdx.x;
    if (b < 298) {
        int row = b*2 + (threadIdx.x >> 7);
        int j   = threadIdx.x & 127;
        if (row >= NUM_REL + NUM_TS) return;
        const float* tbl; const float* Wb; float* out;
        if (row < NUM_REL) { tbl = rel_table + row*HID;            Wb = W_rt;          out = relP + row*D; }
        else               { tbl = time_table + (row-NUM_REL)*HID; Wb = W_rt + HID*D;  out = timP + (row-NUM_REL)*D; }
        float acc = 0.f;
        #pragma unroll
        for (int k = 0; k < HID; ++k) acc += tbl[k] * Wb[k*D + j];
        out[j] = acc;
    } else {
        int id = (b - 298)*256 + threadIdx.x;   // 0..6143
        if (id < 4096) {                 // W13 frags
            int mt = id >> 8;            // 0..15
            int s  = (id >> 6) & 3;
            int l  = id & 63;
            int m  = mt*16 + (l & 15);   // output col 0..255
            int kb = s*32 + (l >> 4)*8;
            unsigned short* dst = Wpk13 + ((size_t)(mt*4 + s)*64 + l)*8;
            #pragma unroll
            for (int j = 0; j < 8; ++j) {
                int k = kb + j;
                float v = (m < D) ? W_fc[(size_t)k*D + m]
                                  : W_fc[(size_t)(256 + k)*D + (m - D)];
                dst[j] = (unsigned short)bf_rne(v);
            }
        } else {                         // W2 frags
            int id2 = id - 4096;
            int mt = id2 >> 8;           // 0..7
            int s  = (id2 >> 6) & 3;
            int l  = id2 & 63;
            int m  = mt*16 + (l & 15);
            int kb = s*32 + (l >> 4)*8;
            unsigned short* dst = Wpk2 + ((size_t)(mt*4 + s)*64 + l)*8;
            #pragma unroll
            for (int j = 0; j < 8; ++j) {
                int k = kb + j;
                dst[j] = (unsigned short)bf_rne(W_fc[(size_t)(D + k)*D + m]);
            }
        }
    }
}

// ---------------------------------------------------------------------------
// k_mm — round-5 structure (Bresenham scatter interleave: scatter hides
// under MFMA blocks, measured +12 µs vs +30 standalone) with register-economy
// rebuild of the MFMA bodies:
//  * AGPR insight (round-8): acc lives in AGPRs, which share the unified
//    reg file. xw's old acc[4][4] = 64 AGPR + 52 VGPR ≈ 116/wave -> only
//    ~16 waves/CU. xw now runs TWO mi-half passes with acc[2][4] (32 AGPR),
//    each half s-fully-unrolled so its 8 af L2-loads issue up-front
//    (fixes the serial af->MFMA chain without round-7's 148-reg cliff).
//  * t2: s-loop fully unrolled (compiler hoists the 8 af loads).
// ---------------------------------------------------------------------------
__device__ __forceinline__ void xw_body(
        int xb, const float* __restrict__ x,
        const unsigned short* __restrict__ Wpk13,
        unsigned short* __restrict__ xW13bf, int n_nodes,
        unsigned short* Xs /* 64*XPAD */)
{
    int t = threadIdx.x;
    int nodeBase = xb*64;
    {   // stage X tile (fp32 -> bf16), 4 threads per node row
        int row = t >> 2;
        int k0  = (t & 3)*32;
        int node = nodeBase + row;
        unsigned short* dst = Xs + row*XPAD + k0;
        if (node < n_nodes) {
            const float4* src = (const float4*)(x + (size_t)node*D + k0);
            #pragma unroll
            for (int g = 0; g < 8; ++g) {
                float4 v = src[g];
                *(uint2*)(dst + g*4) = make_uint2(pk2(v.x, v.y), pk2(v.z, v.w));
            }
        } else {
            #pragma unroll
            for (int g = 0; g < 8; ++g)
                *(uint2*)(dst + g*4) = make_uint2(0u, 0u);
        }
    }
    __syncthreads();

    int w = t >> 6, l = t & 63;
    int li = l & 15, q = l >> 4;

    #pragma unroll 1            // MUST stay rolled: both halves' acc live
    for (int half = 0; half < 2; ++half) {
        f32x4 acc[2][4];
        #pragma unroll
        for (int mi = 0; mi < 2; ++mi)
            #pragma unroll
            for (int ni = 0; ni < 4; ++ni) acc[mi][ni] = (f32x4){0.f,0.f,0.f,0.f};

        #pragma unroll          // full s unroll: 8 independent af loads up-front
        for (int s = 0; s < 4; ++s) {
            short8 af[2], bf[4];
            #pragma unroll
            for (int mi = 0; mi < 2; ++mi) {
                int mt = w*4 + half*2 + mi;
                af[mi] = *(const short8*)(Wpk13 + ((size_t)(mt*4 + s)*64 + l)*8);
            }
            #pragma unroll
            for (int ni = 0; ni < 4; ++ni)
                bf[ni] = *(const short8*)(Xs + (ni*16 + li)*XPAD + s*32 + q*8);
            #pragma unroll
            for (int mi = 0; mi < 2; ++mi)
                #pragma unroll
                for (int ni = 0; ni < 4; ++ni)
                    acc[mi][ni] = __builtin_amdgcn_mfma_f32_16x16x32_bf16(
                                      af[mi], bf[ni], acc[mi][ni], 0, 0, 0);
        }
        #pragma unroll
        for (int ni = 0; ni < 4; ++ni) {
            int node = nodeBase + ni*16 + li;
            if (node >= n_nodes) continue;
            #pragma unroll
            for (int mi = 0; mi < 2; ++mi) {
                int col = (w*4 + half*2 + mi)*16 + q*4;
                *(uint2*)(xW13bf + (size_t)node*256 + col) =
                    make_uint2(pk2(acc[mi][ni][0], acc[mi][ni][1]),
                               pk2(acc[mi][ni][2], acc[mi][ni][3]));
            }
        }
    }
}

__device__ __forceinline__ void t2_body(
        int tb, const float* __restrict__ relP, const float* __restrict__ timP,
        const float* __restrict__ b_rt, const unsigned short* __restrict__ Wpk2,
        unsigned short* __restrict__ T2bf,
        unsigned short* Hs /* 64*XPAD */)
{
    int t = threadIdx.x;
    int cBase = tb*64;
    {   // stage H tile: lrelu(relP+timP+b) -> bf16, 4 threads per row
        int r  = t >> 2;
        int hk = (t & 3)*32;
        int combo = cBase + r;
        if (combo >= NCOMB) combo = NCOMB - 1;
        int rr = combo / NUM_TS;
        int tt = combo - rr*NUM_TS;
        const float4* rv4 = (const float4*)(relP + (size_t)rr*D + hk);
        const float4* tv4 = (const float4*)(timP + (size_t)tt*D + hk);
        const float4* bv4 = (const float4*)(b_rt + hk);
        unsigned short* dst = Hs + r*XPAD + hk;
        #pragma unroll
        for (int g = 0; g < 8; ++g) {
            float4 rv = rv4[g], tv = tv4[g], bv = bv4[g];
            float v0 = lrelu(rv.x+tv.x+bv.x), v1 = lrelu(rv.y+tv.y+bv.y);
            float v2 = lrelu(rv.z+tv.z+bv.z), v3 = lrelu(rv.w+tv.w+bv.w);
            *(uint2*)(dst + g*4) = make_uint2(pk2(v0,v1), pk2(v2,v3));
        }
    }
    __syncthreads();

    int w = t >> 6, l = t & 63;
    int li = l & 15, q = l >> 4;

    f32x4 acc[2][4];
    #pragma unroll
    for (int mi = 0; mi < 2; ++mi)
        #pragma unroll
        for (int ni = 0; ni < 4; ++ni) acc[mi][ni] = (f32x4){0.f,0.f,0.f,0.f};

    #pragma unroll              // full s unroll: compiler hoists the 8 af loads
    for (int s = 0; s < 4; ++s) {
        short8 af[2], bf[4];
        #pragma unroll
        for (int mi = 0; mi < 2; ++mi) {
            int mt = w*2 + mi;
            af[mi] = *(const short8*)(Wpk2 + ((size_t)(mt*4 + s)*64 + l)*8);
        }
        #pragma unroll
        for (int ni = 0; ni < 4; ++ni)
            bf[ni] = *(const short8*)(Hs + (ni*16 + li)*XPAD + s*32 + q*8);
        #pragma unroll
        for (int mi = 0; mi < 2; ++mi)
            #pragma unroll
            for (int ni = 0; ni < 4; ++ni)
                acc[mi][ni] = __builtin_amdgcn_mfma_f32_16x16x32_bf16(
                                  af[mi], bf[ni], acc[mi][ni], 0, 0, 0);
    }
    #pragma unroll
    for (int ni = 0; ni < 4; ++ni) {
        int combo = cBase + ni*16 + li;
        if (combo >= NCOMB) continue;
        #pragma unroll
        for (int mi = 0; mi < 2; ++mi) {
            int col = (w*2 + mi)*16 + q*4;
            *(uint2*)(T2bf + (size_t)combo*D + col) =
                make_uint2(pk2(acc[mi][ni][0], acc[mi][ni][1]),
                           pk2(acc[mi][ni][2], acc[mi][ni][3]));
        }
    }
}

__global__ __launch_bounds__(256, 3) void k_mm(
        const float* __restrict__ x, const unsigned short* __restrict__ Wpk13,
        unsigned short* __restrict__ xW13bf, int n_nodes,
        const float* __restrict__ relP, const float* __restrict__ timP,
        const float* __restrict__ b_rt, const unsigned short* __restrict__ Wpk2,
        unsigned short* __restrict__ T2bf,
        const int* __restrict__ edges, int n_edges,
        int* __restrict__ deg, int2* __restrict__ ebuf,
        int nsc, int nxw, int ntot)
{
    __shared__ __align__(16) unsigned short Hs[64*XPAD];  // 17.4 KB (union)
    int b = blockIdx.x;
    // Bresenham interleave: scatter block iff cumulative count increments.
    int cumCur  = (int)(((long long)b       * nsc) / ntot);
    int cumNext = (int)(((long long)(b + 1) * nsc) / ntot);
    if (cumNext > cumCur) {
        // edge bucket-scatter (latency-bound; hides under co-resident MFMA
        // blocks: +12 µs vs +30 standalone). deg zeroed by hipMemsetAsync
        // blit (round-3 lesson: plain-store zeroing -> stale atomics).
        int e = cumCur*256 + threadIdx.x;
        if (e < n_edges) {
            int4 ed = ((const int4*)edges)[e];
            int slot = atomicAdd(&deg[ed.y], 1);
            if (slot < MAXDEG)   // safety clamp; statistically never taken
                ebuf[(size_t)ed.y*MAXDEG + slot] = make_int2(ed.x, ed.z*NUM_TS + ed.w);
        }
    } else {
        int cidx = b - cumNext;
        if (cidx < nxw) {
            xw_body(cidx, x, Wpk13, xW13bf, n_nodes, Hs);
        } else {
            t2_body(cidx - nxw, relP, timP, b_rt, Wpk2, T2bf, Hs);
        }
    }
}

// ---------------------------------------------------------------------------
// k_agg: 4 nodes per wave, 16 lanes per node, uint4 (16B) gathers.
// (unchanged — ~3.1 TB/s on the random 256B-row gather path, near its floor)
// ---------------------------------------------------------------------------
__global__ __launch_bounds__(256) void k_agg(
        const int* __restrict__ deg, const int2* __restrict__ ebuf,
        const unsigned short* __restrict__ xW13bf,
        const unsigned short* __restrict__ T2bf,
        const float* __restrict__ b_fc,
        float* __restrict__ out, int n_nodes)
{
    int t    = threadIdx.x;
    int lane = t & 63;
    int g    = lane >> 4;             // node group within wave (0..3)
    int sub  = lane & 15;             // lane within group; covers cols sub*8..+7
    int node = blockIdx.x*16 + (t >> 6)*4 + g;
    bool valid = node < n_nodes;
    int nodeC  = valid ? node : n_nodes - 1;

    int dg  = deg[nodeC];
    int cnt = valid ? (dg < MAXDEG ? dg : MAXDEG) : 0;
    int cm1 = cnt > 0 ? cnt - 1 : 0;
    const int2* eb = ebuf + (size_t)nodeC * MAXDEG;

    // wave-max trip count (cnt is uniform within each 16-lane group)
    int cmax = cnt;
    cmax = max(cmax, __shfl_xor(cmax, 16));
    cmax = max(cmax, __shfl_xor(cmax, 32));

    // base = xW3[node] + b_fc for this lane's 8 cols
    float base[8];
    {
        uint4  w3  = *(const uint4*)&xW13bf[(size_t)nodeC*256 + 128 + sub*8];
        float4 blo = *(const float4*)&b_fc[sub*8];
        float4 bhi = *(const float4*)&b_fc[sub*8 + 4];
        base[0] = bf_lo(w3.x) + blo.x; base[1] = bf_hi(w3.x) + blo.y;
        base[2] = bf_lo(w3.y) + blo.z; base[3] = bf_hi(w3.y) + blo.w;
        base[4] = bf_lo(w3.z) + bhi.x; base[5] = bf_hi(w3.z) + bhi.y;
        base[6] = bf_lo(w3.w) + bhi.z; base[7] = bf_hi(w3.w) + bhi.w;
    }

    float acc[8];
    #pragma unroll
    for (int k = 0; k < 8; ++k) acc[k] = 0.f;

    const unsigned sMax = (unsigned)(n_nodes - 1);
    const unsigned cMax = (unsigned)(NCOMB - 1);

    for (int e = 0; e < cmax; e += 4) {
        // --- batch 1: index loads (independent, clamped in-bounds) ---
        int2 e0 = eb[min(e + 0, cm1)];
        int2 e1 = eb[min(e + 1, cm1)];
        int2 e2 = eb[min(e + 2, cm1)];
        int2 e3 = eb[min(e + 3, cm1)];
        // --- clamp gather targets (garbage-safe for masked slots) ---
        unsigned s0 = min((unsigned)e0.x, sMax), c0 = min((unsigned)e0.y, cMax);
        unsigned s1 = min((unsigned)e1.x, sMax), c1 = min((unsigned)e1.y, cMax);
        unsigned s2 = min((unsigned)e2.x, sMax), c2 = min((unsigned)e2.y, cMax);
        unsigned s3 = min((unsigned)e3.x, sMax), c3 = min((unsigned)e3.y, cMax);
        // --- batch 2: 8 independent 16B gathers ---
        uint4 S0 = *(const uint4*)&xW13bf[(size_t)s0*256 + sub*8];
        uint4 T0 = *(const uint4*)&T2bf  [(size_t)c0*D   + sub*8];
        uint4 S1 = *(const uint4*)&xW13bf[(size_t)s1*256 + sub*8];
        uint4 T1 = *(const uint4*)&T2bf  [(size_t)c1*D   + sub*8];
        uint4 S2 = *(const uint4*)&xW13bf[(size_t)s2*256 + sub*8];
        uint4 T2 = *(const uint4*)&T2bf  [(size_t)c2*D   + sub*8];
        uint4 S3 = *(const uint4*)&xW13bf[(size_t)s3*256 + sub*8];
        uint4 T3 = *(const uint4*)&T2bf  [(size_t)c3*D   + sub*8];
        // --- consume (cndmask-masked; no divergent control flow) ---
        bool m0 = (e + 0) < cnt, m1 = (e + 1) < cnt;
        bool m2 = (e + 2) < cnt, m3 = (e + 3) < cnt;
        #pragma unroll
        for (int w = 0; w < 4; ++w) {
            unsigned Sw0 = (&S0.x)[w], Tw0 = (&T0.x)[w];
            unsigned Sw1 = (&S1.x)[w], Tw1 = (&T1.x)[w];
            unsigned Sw2 = (&S2.x)[w], Tw2 = (&T2.x)[w];
            unsigned Sw3 = (&S3.x)[w], Tw3 = (&T3.x)[w];
            float v0l = lrelu(bf_lo(Sw0) + bf_lo(Tw0) + base[2*w]);
            float v0h = lrelu(bf_hi(Sw0) + bf_hi(Tw0) + base[2*w+1]);
            float v1l = lrelu(bf_lo(Sw1) + bf_lo(Tw1) + base[2*w]);
            float v1h = lrelu(bf_hi(Sw1) + bf_hi(Tw1) + base[2*w+1]);
            float v2l = lrelu(bf_lo(Sw2) + bf_lo(Tw2) + base[2*w]);
            float v2h = lrelu(bf_hi(Sw2) + bf_hi(Tw2) + base[2*w+1]);
            float v3l = lrelu(bf_lo(Sw3) + bf_lo(Tw3) + base[2*w]);
            float v3h = lrelu(bf_hi(Sw3) + bf_hi(Tw3) + base[2*w+1]);
            float a01l = (m0 ? v0l : 0.f) + (m1 ? v1l : 0.f);
            float a23l = (m2 ? v2l : 0.f) + (m3 ? v3l : 0.f);
            float a01h = (m0 ? v0h : 0.f) + (m1 ? v1h : 0.f);
            float a23h = (m2 ? v2h : 0.f) + (m3 ? v3h : 0.f);
            acc[2*w]   += a01l + a23l;
            acc[2*w+1] += a01h + a23h;
        }
    }

    if (!valid) return;
    float inv = 1.f / fmaxf((float)dg, 1.f);
    float4 o0 = make_float4(acc[0]*inv, acc[1]*inv, acc[2]*inv, acc[3]*inv);
    float4 o1 = make_float4(acc[4]*inv, acc[5]*inv, acc[6]*inv, acc[7]*inv);
    *(float4*)&out[(size_t)node*D + sub*8]     = o0;
    *(float4*)&out[(size_t)node*D + sub*8 + 4] = o1;
}

// ---------------------------------------------------------------------------
extern "C" void kernel_launch(void* const* d_in, const int* in_sizes, int n_in,
                              void* d_out, int out_size, void* d_ws, size_t ws_size,
                              hipStream_t stream)
{
    const float* x          = (const float*)d_in[0];
    const float* rel_table  = (const float*)d_in[1];
    const float* time_table = (const float*)d_in[2];
    const float* W_rt       = (const float*)d_in[3];
    const float* b_rt       = (const float*)d_in[4];
    const float* W_fc       = (const float*)d_in[5];
    const float* b_fc       = (const float*)d_in[6];
    const int*   edges      = (const int*)d_in[7];

    int n_nodes = in_sizes[0] / D;   // 50000
    int n_edges = in_sizes[7] / 4;   // 400000
    int nsc     = (n_edges + 255) / 256;   // 1563 scatter blocks (1 e/thr, r5)
    int nxw     = (n_nodes + 63) / 64;     // 782
    int nt2     = (NCOMB + 63) / 64;       // 1312
    int ntot    = nsc + nxw + nt2;         // 3657

    char* ws = (char*)d_ws;
    size_t off = 0;
    auto alloc = [&](size_t bytes) -> void* {
        void* p = ws + off; off += (bytes + 255) & ~(size_t)255; return p;
    };
    unsigned short* xW13bf = (unsigned short*)alloc((size_t)n_nodes * 256 * 2); // 25.6 MB
    unsigned short* T2bf   = (unsigned short*)alloc((size_t)NCOMB * D * 2);     // 21.5 MB
    unsigned short* Wpk13  = (unsigned short*)alloc((size_t)16*4*64*8 * 2);     // 64 KB
    unsigned short* Wpk2   = (unsigned short*)alloc((size_t)8*4*64*8 * 2);      // 32 KB
    float* relP   = (float*)alloc((size_t)NUM_REL * D * sizeof(float));
    float* timP   = (float*)alloc((size_t)NUM_TS * D * sizeof(float));
    int*   deg    = (int*)alloc((size_t)n_nodes * sizeof(int));
    int2*  ebuf   = (int2*)alloc((size_t)n_nodes * MAXDEG * sizeof(int2));      // 25.6 MB
    if (off > ws_size)
        fprintf(stderr, "kernel_launch: workspace too small: need %zu, have %zu\n", off, ws_size);

    hipMemsetAsync(deg, 0, (size_t)n_nodes * sizeof(int), stream);

    k_prep<<<322, 256, 0, stream>>>(rel_table, time_table, W_rt, W_fc,
                                    relP, timP, Wpk13, Wpk2);
    k_mm  <<<ntot, 256, 0, stream>>>(x, Wpk13, xW13bf, n_nodes,
                                     relP, timP, b_rt, Wpk2, T2bf,
                                     edges, n_edges, deg, ebuf,
                                     nsc, nxw, ntot);
    k_agg <<<(n_nodes + 15)/16, 256, 0, stream>>>(deg, ebuf, xW13bf, T2bf,
                                                  b_fc, (float*)d_out, n_nodes);
}

// Round 11
// 166.955 us; speedup vs baseline: 1.1252x; 1.0243x over previous
//
#include <hip/hip_runtime.h>
#include <cstdio>

#define HID 64
#define D 128            // 2*HID
#define NUM_REL 230
#define NUM_TS 365
#define NCOMB (NUM_REL*NUM_TS)   // 83950
#define SLOPE 0.2f
#define XPAD 136         // LDS row stride in bf16
#define MAXDEG 64        // Poisson(8) max degree ~25; P(deg>=64) < 1e-40

typedef __attribute__((ext_vector_type(8))) short short8;
typedef __attribute__((ext_vector_type(4))) float f32x4;

__device__ __forceinline__ float lrelu(float v){ return v >= 0.f ? v : SLOPE*v; }

// bf16 helpers
__device__ __forceinline__ unsigned bf_rne(float f){
    unsigned u = __float_as_uint(f);
    return (u + 0x7fffu + ((u >> 16) & 1u)) >> 16;
}
__device__ __forceinline__ unsigned pk2(float a, float b){
    return bf_rne(a) | (bf_rne(b) << 16);
}
__device__ __forceinline__ float bf_lo(unsigned u){ return __uint_as_float(u << 16); }
__device__ __forceinline__ float bf_hi(unsigned u){ return __uint_as_float(u & 0xffff0000u); }

// ---------------------------------------------------------------------------
// k_prep: parts (relP/timP) + W-pack ONLY.  (round-5 form, ~12 µs)
// ---------------------------------------------------------------------------
__global__ __launch_bounds__(256) void k_prep(
        const float* __restrict__ rel_table, const float* __restrict__ time_table,
        const float* __restrict__ W_rt, const float* __restrict__ W_fc,
        float* __restrict__ relP, float* __restrict__ timP,
        unsigned short* __restrict__ Wpk13, unsigned short* __restrict__ Wpk2)
{
    int b = blockIdx.x;
    if (b < 298) {
        int row = b*2 + (threadIdx.x >> 7);
        int j   = threadIdx.x & 127;
        if (row >= NUM_REL + NUM_TS) return;
        const float* tbl; const float* Wb; float* out;
        if (row < NUM_REL) { tbl = rel_table + row*HID;            Wb = W_rt;          out = relP + row*D; }
        else               { tbl = time_table + (row-NUM_REL)*HID; Wb = W_rt + HID*D;  out = timP + (row-NUM_REL)*D; }
        float acc = 0.f;
        #pragma unroll
        for (int k = 0; k < HID; ++k) acc += tbl[k] * Wb[k*D + j];
        out[j] = acc;
    } else {
        int id = (b - 298)*256 + threadIdx.x;   // 0..6143
        if (id < 4096) {                 // W13 frags
            int mt = id >> 8;            // 0..15
            int s  = (id >> 6) & 3;
            int l  = id & 63;
            int m  = mt*16 + (l & 15);   // output col 0..255
            int kb = s*32 + (l >> 4)*8;
            unsigned short* dst = Wpk13 + ((size_t)(mt*4 + s)*64 + l)*8;
            #pragma unroll
            for (int j = 0; j < 8; ++j) {
                int k = kb + j;
                float v = (m < D) ? W_fc[(size_t)k*D + m]
                                  : W_fc[(size_t)(256 + k)*D + (m - D)];
                dst[j] = (unsigned short)bf_rne(v);
            }
        } else {                         // W2 frags
            int id2 = id - 4096;
            int mt = id2 >> 8;           // 0..7
            int s  = (id2 >> 6) & 3;
            int l  = id2 & 63;
            int m  = mt*16 + (l & 15);
            int kb = s*32 + (l >> 4)*8;
            unsigned short* dst = Wpk2 + ((size_t)(mt*4 + s)*64 + l)*8;
            #pragma unroll
            for (int j = 0; j < 8; ++j) {
                int k = kb + j;
                dst[j] = (unsigned short)bf_rne(W_fc[(size_t)(D + k)*D + m]);
            }
        }
    }
}

// ---------------------------------------------------------------------------
// k_mm — r5 skeleton; mm epilogues rebuilt (round-10 theory): acc is staged
// through a 16KB LDS tile (Cs) and stored with a lane-contiguous flat map so
// every store instruction writes 1KB of FULLY-covered 64B lines.
// Old pattern: 8B/lane at 512B stride = 16 partial 32B line-writes per instr
// (~8x transaction amplification) — candidate for the unexplained ~30 µs.
//  * xw: two column-halves (acc[2][4], s-rolled = r8's proven 52-VGPR shape),
//    each half's C-tile = 64 nodes x 128 cols bf16 = 16KB exactly.
//  * t2: single pass; stores become perfectly contiguous 256B/combo rows.
// LDS = 17.4K (Hs/Xs) + 16K (Cs) = 33.8KB; LDS allows 4.7 blk/CU > reg ~2.5.
// ---------------------------------------------------------------------------
__device__ __forceinline__ void xw_body(
        int xb, const float* __restrict__ x,
        const unsigned short* __restrict__ Wpk13,
        unsigned short* __restrict__ xW13bf, int n_nodes,
        unsigned short* Xs /* 64*XPAD */, unsigned short* Cs /* 64*128 */)
{
    int t = threadIdx.x;
    int nodeBase = xb*64;
    {   // stage X tile (fp32 -> bf16), 4 threads per node row
        int row = t >> 2;
        int k0  = (t & 3)*32;
        int node = nodeBase + row;
        unsigned short* dst = Xs + row*XPAD + k0;
        if (node < n_nodes) {
            const float4* src = (const float4*)(x + (size_t)node*D + k0);
            #pragma unroll
            for (int g = 0; g < 8; ++g) {
                float4 v = src[g];
                *(uint2*)(dst + g*4) = make_uint2(pk2(v.x, v.y), pk2(v.z, v.w));
            }
        } else {
            #pragma unroll
            for (int g = 0; g < 8; ++g)
                *(uint2*)(dst + g*4) = make_uint2(0u, 0u);
        }
    }
    __syncthreads();

    int w = t >> 6, l = t & 63;
    int li = l & 15, q = l >> 4;

    #pragma unroll 1            // halves sequential (acc reuse, reg economy)
    for (int h = 0; h < 2; ++h) {
        f32x4 acc[2][4];
        #pragma unroll
        for (int mi = 0; mi < 2; ++mi)
            #pragma unroll
            for (int ni = 0; ni < 4; ++ni) acc[mi][ni] = (f32x4){0.f,0.f,0.f,0.f};

        #pragma unroll 1
        for (int s = 0; s < 4; ++s) {
            short8 af[2], bf[4];
            #pragma unroll
            for (int mi = 0; mi < 2; ++mi) {
                int mt = w*4 + h*2 + mi;
                af[mi] = *(const short8*)(Wpk13 + ((size_t)(mt*4 + s)*64 + l)*8);
            }
            #pragma unroll
            for (int ni = 0; ni < 4; ++ni)
                bf[ni] = *(const short8*)(Xs + (ni*16 + li)*XPAD + s*32 + q*8);
            #pragma unroll
            for (int mi = 0; mi < 2; ++mi)
                #pragma unroll
                for (int ni = 0; ni < 4; ++ni)
                    acc[mi][ni] = __builtin_amdgcn_mfma_f32_16x16x32_bf16(
                                      af[mi], bf[ni], acc[mi][ni], 0, 0, 0);
        }
        // acc -> Cs (LDS scatter is cheap); local col cl = w*32+mi*16+q*4
        #pragma unroll
        for (int ni = 0; ni < 4; ++ni)
            #pragma unroll
            for (int mi = 0; mi < 2; ++mi) {
                int node = ni*16 + li;
                int cl   = w*32 + mi*16 + q*4;
                *(uint2*)(Cs + node*128 + cl) =
                    make_uint2(pk2(acc[mi][ni][0], acc[mi][ni][1]),
                               pk2(acc[mi][ni][2], acc[mi][ni][3]));
            }
        __syncthreads();
        // coalesced store: per instr, 64 lanes x 16B lane-contiguous = 1KB.
        // global col = (cl>>5)*64 + h*32 + (cl&31)
        #pragma unroll
        for (int k = 0; k < 4; ++k) {
            int flat  = (k*4 + w)*1024 + l*16;   // byte index into 16KB tile
            int nodeL = flat >> 8;
            int off   = flat & 255;
            int node  = nodeBase + nodeL;
            if (node < n_nodes) {
                uint4 v = *(const uint4*)((const char*)Cs + flat);
                *(uint4*)((char*)(xW13bf + (size_t)node*256)
                          + (off >> 6)*128 + h*64 + (off & 63)) = v;
            }
        }
        __syncthreads();   // Cs reads done before next half rewrites it
    }
}

__device__ __forceinline__ void t2_body(
        int tb, const float* __restrict__ relP, const float* __restrict__ timP,
        const float* __restrict__ b_rt, const unsigned short* __restrict__ Wpk2,
        unsigned short* __restrict__ T2bf,
        unsigned short* Hs /* 64*XPAD */, unsigned short* Cs /* 64*128 */)
{
    int t = threadIdx.x;
    int cBase = tb*64;
    {   // stage H tile: lrelu(relP+timP+b) -> bf16, 4 threads per row
        int r  = t >> 2;
        int hk = (t & 3)*32;
        int combo = cBase + r;
        if (combo >= NCOMB) combo = NCOMB - 1;
        int rr = combo / NUM_TS;
        int tt = combo - rr*NUM_TS;
        const float4* rv4 = (const float4*)(relP + (size_t)rr*D + hk);
        const float4* tv4 = (const float4*)(timP + (size_t)tt*D + hk);
        const float4* bv4 = (const float4*)(b_rt + hk);
        unsigned short* dst = Hs + r*XPAD + hk;
        #pragma unroll
        for (int g = 0; g < 8; ++g) {
            float4 rv = rv4[g], tv = tv4[g], bv = bv4[g];
            float v0 = lrelu(rv.x+tv.x+bv.x), v1 = lrelu(rv.y+tv.y+bv.y);
            float v2 = lrelu(rv.z+tv.z+bv.z), v3 = lrelu(rv.w+tv.w+bv.w);
            *(uint2*)(dst + g*4) = make_uint2(pk2(v0,v1), pk2(v2,v3));
        }
    }
    __syncthreads();

    int w = t >> 6, l = t & 63;
    int li = l & 15, q = l >> 4;

    f32x4 acc[2][4];
    #pragma unroll
    for (int mi = 0; mi < 2; ++mi)
        #pragma unroll
        for (int ni = 0; ni < 4; ++ni) acc[mi][ni] = (f32x4){0.f,0.f,0.f,0.f};

    #pragma unroll 1
    for (int s = 0; s < 4; ++s) {
        short8 af[2], bf[4];
        #pragma unroll
        for (int mi = 0; mi < 2; ++mi) {
            int mt = w*2 + mi;
            af[mi] = *(const short8*)(Wpk2 + ((size_t)(mt*4 + s)*64 + l)*8);
        }
        #pragma unroll
        for (int ni = 0; ni < 4; ++ni)
            bf[ni] = *(const short8*)(Hs + (ni*16 + li)*XPAD + s*32 + q*8);
        #pragma unroll
        for (int mi = 0; mi < 2; ++mi)
            #pragma unroll
            for (int ni = 0; ni < 4; ++ni)
                acc[mi][ni] = __builtin_amdgcn_mfma_f32_16x16x32_bf16(
                                  af[mi], bf[ni], acc[mi][ni], 0, 0, 0);
    }
    // acc -> Cs; local col = (w*2+mi)*16 + q*4 = global col directly
    #pragma unroll
    for (int ni = 0; ni < 4; ++ni)
        #pragma unroll
        for (int mi = 0; mi < 2; ++mi) {
            int comboL = ni*16 + li;
            int cl     = (w*2 + mi)*16 + q*4;
            *(uint2*)(Cs + comboL*128 + cl) =
                make_uint2(pk2(acc[mi][ni][0], acc[mi][ni][1]),
                           pk2(acc[mi][ni][2], acc[mi][ni][3]));
        }
    __syncthreads();
    // coalesced store: T2bf rows are 256B contiguous -> perfect 1KB/instr
    #pragma unroll
    for (int k = 0; k < 4; ++k) {
        int flat = (k*4 + w)*1024 + l*16;
        int cL   = flat >> 8;
        int off  = flat & 255;
        int combo = cBase + cL;
        if (combo < NCOMB) {
            uint4 v = *(const uint4*)((const char*)Cs + flat);
            *(uint4*)((char*)(T2bf + (size_t)combo*D) + off) = v;
        }
    }
}

__global__ __launch_bounds__(256, 3) void k_mm(
        const float* __restrict__ x, const unsigned short* __restrict__ Wpk13,
        unsigned short* __restrict__ xW13bf, int n_nodes,
        const float* __restrict__ relP, const float* __restrict__ timP,
        const float* __restrict__ b_rt, const unsigned short* __restrict__ Wpk2,
        unsigned short* __restrict__ T2bf,
        const int* __restrict__ edges, int n_edges,
        int* __restrict__ deg, int2* __restrict__ ebuf,
        int nsc, int nxw, int ntot)
{
    __shared__ __align__(16) unsigned short Hs[64*XPAD];  // 17.4 KB
    __shared__ __align__(16) unsigned short Cs[64*128];   // 16.0 KB
    int b = blockIdx.x;
    // Bresenham interleave: scatter block iff cumulative count increments.
    int cumCur  = (int)(((long long)b       * nsc) / ntot);
    int cumNext = (int)(((long long)(b + 1) * nsc) / ntot);
    if (cumNext > cumCur) {
        // edge bucket-scatter (hides under co-resident MFMA blocks:
        // +12 µs vs +30 standalone). deg zeroed by hipMemsetAsync blit
        // (round-3 lesson: plain-store zeroing -> stale atomics).
        int e = cumCur*256 + threadIdx.x;
        if (e < n_edges) {
            int4 ed = ((const int4*)edges)[e];
            int slot = atomicAdd(&deg[ed.y], 1);
            if (slot < MAXDEG)   // safety clamp; statistically never taken
                ebuf[(size_t)ed.y*MAXDEG + slot] = make_int2(ed.x, ed.z*NUM_TS + ed.w);
        }
    } else {
        int cidx = b - cumNext;
        if (cidx < nxw) {
            xw_body(cidx, x, Wpk13, xW13bf, n_nodes, Hs, Cs);
        } else {
            t2_body(cidx - nxw, relP, timP, b_rt, Wpk2, T2bf, Hs, Cs);
        }
    }
}

// ---------------------------------------------------------------------------
// k_agg: 4 nodes per wave, 16 lanes per node, uint4 (16B) gathers.
// (unchanged — at the random-gather floor for this access pattern)
// ---------------------------------------------------------------------------
__global__ __launch_bounds__(256) void k_agg(
        const int* __restrict__ deg, const int2* __restrict__ ebuf,
        const unsigned short* __restrict__ xW13bf,
        const unsigned short* __restrict__ T2bf,
        const float* __restrict__ b_fc,
        float* __restrict__ out, int n_nodes)
{
    int t    = threadIdx.x;
    int lane = t & 63;
    int g    = lane >> 4;             // node group within wave (0..3)
    int sub  = lane & 15;             // lane within group; covers cols sub*8..+7
    int node = blockIdx.x*16 + (t >> 6)*4 + g;
    bool valid = node < n_nodes;
    int nodeC  = valid ? node : n_nodes - 1;

    int dg  = deg[nodeC];
    int cnt = valid ? (dg < MAXDEG ? dg : MAXDEG) : 0;
    int cm1 = cnt > 0 ? cnt - 1 : 0;
    const int2* eb = ebuf + (size_t)nodeC * MAXDEG;

    // wave-max trip count (cnt is uniform within each 16-lane group)
    int cmax = cnt;
    cmax = max(cmax, __shfl_xor(cmax, 16));
    cmax = max(cmax, __shfl_xor(cmax, 32));

    // base = xW3[node] + b_fc for this lane's 8 cols
    float base[8];
    {
        uint4  w3  = *(const uint4*)&xW13bf[(size_t)nodeC*256 + 128 + sub*8];
        float4 blo = *(const float4*)&b_fc[sub*8];
        float4 bhi = *(const float4*)&b_fc[sub*8 + 4];
        base[0] = bf_lo(w3.x) + blo.x; base[1] = bf_hi(w3.x) + blo.y;
        base[2] = bf_lo(w3.y) + blo.z; base[3] = bf_hi(w3.y) + blo.w;
        base[4] = bf_lo(w3.z) + bhi.x; base[5] = bf_hi(w3.z) + bhi.y;
        base[6] = bf_lo(w3.w) + bhi.z; base[7] = bf_hi(w3.w) + bhi.w;
    }

    float acc[8];
    #pragma unroll
    for (int k = 0; k < 8; ++k) acc[k] = 0.f;

    const unsigned sMax = (unsigned)(n_nodes - 1);
    const unsigned cMax = (unsigned)(NCOMB - 1);

    for (int e = 0; e < cmax; e += 4) {
        // --- batch 1: index loads (independent, clamped in-bounds) ---
        int2 e0 = eb[min(e + 0, cm1)];
        int2 e1 = eb[min(e + 1, cm1)];
        int2 e2 = eb[min(e + 2, cm1)];
        int2 e3 = eb[min(e + 3, cm1)];
        // --- clamp gather targets (garbage-safe for masked slots) ---
        unsigned s0 = min((unsigned)e0.x, sMax), c0 = min((unsigned)e0.y, cMax);
        unsigned s1 = min((unsigned)e1.x, sMax), c1 = min((unsigned)e1.y, cMax);
        unsigned s2 = min((unsigned)e2.x, sMax), c2 = min((unsigned)e2.y, cMax);
        unsigned s3 = min((unsigned)e3.x, sMax), c3 = min((unsigned)e3.y, cMax);
        // --- batch 2: 8 independent 16B gathers ---
        uint4 S0 = *(const uint4*)&xW13bf[(size_t)s0*256 + sub*8];
        uint4 T0 = *(const uint4*)&T2bf  [(size_t)c0*D   + sub*8];
        uint4 S1 = *(const uint4*)&xW13bf[(size_t)s1*256 + sub*8];
        uint4 T1 = *(const uint4*)&T2bf  [(size_t)c1*D   + sub*8];
        uint4 S2 = *(const uint4*)&xW13bf[(size_t)s2*256 + sub*8];
        uint4 T2 = *(const uint4*)&T2bf  [(size_t)c2*D   + sub*8];
        uint4 S3 = *(const uint4*)&xW13bf[(size_t)s3*256 + sub*8];
        uint4 T3 = *(const uint4*)&T2bf  [(size_t)c3*D   + sub*8];
        // --- consume (cndmask-masked; no divergent control flow) ---
        bool m0 = (e + 0) < cnt, m1 = (e + 1) < cnt;
        bool m2 = (e + 2) < cnt, m3 = (e + 3) < cnt;
        #pragma unroll
        for (int w = 0; w < 4; ++w) {
            unsigned Sw0 = (&S0.x)[w], Tw0 = (&T0.x)[w];
            unsigned Sw1 = (&S1.x)[w], Tw1 = (&T1.x)[w];
            unsigned Sw2 = (&S2.x)[w], Tw2 = (&T2.x)[w];
            unsigned Sw3 = (&S3.x)[w], Tw3 = (&T3.x)[w];
            float v0l = lrelu(bf_lo(Sw0) + bf_lo(Tw0) + base[2*w]);
            float v0h = lrelu(bf_hi(Sw0) + bf_hi(Tw0) + base[2*w+1]);
            float v1l = lrelu(bf_lo(Sw1) + bf_lo(Tw1) + base[2*w]);
            float v1h = lrelu(bf_hi(Sw1) + bf_hi(Tw1) + base[2*w+1]);
            float v2l = lrelu(bf_lo(Sw2) + bf_lo(Tw2) + base[2*w]);
            float v2h = lrelu(bf_hi(Sw2) + bf_hi(Tw2) + base[2*w+1]);
            float v3l = lrelu(bf_lo(Sw3) + bf_lo(Tw3) + base[2*w]);
            float v3h = lrelu(bf_hi(Sw3) + bf_hi(Tw3) + base[2*w+1]);
            float a01l = (m0 ? v0l : 0.f) + (m1 ? v1l : 0.f);
            float a23l = (m2 ? v2l : 0.f) + (m3 ? v3l : 0.f);
            float a01h = (m0 ? v0h : 0.f) + (m1 ? v1h : 0.f);
            float a23h = (m2 ? v2h : 0.f) + (m3 ? v3h : 0.f);
            acc[2*w]   += a01l + a23l;
            acc[2*w+1] += a01h + a23h;
        }
    }

    if (!valid) return;
    float inv = 1.f / fmaxf((float)dg, 1.f);
    float4 o0 = make_float4(acc[0]*inv, acc[1]*inv, acc[2]*inv, acc[3]*inv);
    float4 o1 = make_float4(acc[4]*inv, acc[5]*inv, acc[6]*inv, acc[7]*inv);
    *(float4*)&out[(size_t)node*D + sub*8]     = o0;
    *(float4*)&out[(size_t)node*D + sub*8 + 4] = o1;
}

// ---------------------------------------------------------------------------
extern "C" void kernel_launch(void* const* d_in, const int* in_sizes, int n_in,
                              void* d_out, int out_size, void* d_ws, size_t ws_size,
                              hipStream_t stream)
{
    const float* x          = (const float*)d_in[0];
    const float* rel_table  = (const float*)d_in[1];
    const float* time_table = (const float*)d_in[2];
    const float* W_rt       = (const float*)d_in[3];
    const float* b_rt       = (const float*)d_in[4];
    const float* W_fc       = (const float*)d_in[5];
    const float* b_fc       = (const float*)d_in[6];
    const int*   edges      = (const int*)d_in[7];

    int n_nodes = in_sizes[0] / D;   // 50000
    int n_edges = in_sizes[7] / 4;   // 400000
    int nsc     = (n_edges + 255) / 256;   // 1563 scatter blocks (1 e/thr, r5)
    int nxw     = (n_nodes + 63) / 64;     // 782
    int nt2     = (NCOMB + 63) / 64;       // 1312
    int ntot    = nsc + nxw + nt2;         // 3657

    char* ws = (char*)d_ws;
    size_t off = 0;
    auto alloc = [&](size_t bytes) -> void* {
        void* p = ws + off; off += (bytes + 255) & ~(size_t)255; return p;
    };
    unsigned short* xW13bf = (unsigned short*)alloc((size_t)n_nodes * 256 * 2); // 25.6 MB
    unsigned short* T2bf   = (unsigned short*)alloc((size_t)NCOMB * D * 2);     // 21.5 MB
    unsigned short* Wpk13  = (unsigned short*)alloc((size_t)16*4*64*8 * 2);     // 64 KB
    unsigned short* Wpk2   = (unsigned short*)alloc((size_t)8*4*64*8 * 2);      // 32 KB
    float* relP   = (float*)alloc((size_t)NUM_REL * D * sizeof(float));
    float* timP   = (float*)alloc((size_t)NUM_TS * D * sizeof(float));
    int*   deg    = (int*)alloc((size_t)n_nodes * sizeof(int));
    int2*  ebuf   = (int2*)alloc((size_t)n_nodes * MAXDEG * sizeof(int2));      // 25.6 MB
    if (off > ws_size)
        fprintf(stderr, "kernel_launch: workspace too small: need %zu, have %zu\n", off, ws_size);

    hipMemsetAsync(deg, 0, (size_t)n_nodes * sizeof(int), stream);

    k_prep<<<322, 256, 0, stream>>>(rel_table, time_table, W_rt, W_fc,
                                    relP, timP, Wpk13, Wpk2);
    k_mm  <<<ntot, 256, 0, stream>>>(x, Wpk13, xW13bf, n_nodes,
                                     relP, timP, b_rt, Wpk2, T2bf,
                                     edges, n_edges, deg, ebuf,
                                     nsc, nxw, ntot);
    k_agg <<<(n_nodes + 15)/16, 256, 0, stream>>>(deg, ebuf, xW13bf, T2bf,
                                                  b_fc, (float*)d_out, n_nodes);
}

// Round 12
// 164.379 us; speedup vs baseline: 1.1429x; 1.0157x over previous
//
#include <hip/hip_runtime.h>
#include <cstdio>

#define HID 64
#define D 128            // 2*HID
#define NUM_REL 230
#define NUM_TS 365
#define NCOMB (NUM_REL*NUM_TS)   // 83950
#define SLOPE 0.2f
#define XPAD 136         // LDS row stride in bf16 (272 B -> bank stride 4, 2-way = free)
#define MAXDEG 64        // Poisson(8) max degree ~25; P(deg>=64) < 1e-40

typedef __attribute__((ext_vector_type(8))) short short8;
typedef __attribute__((ext_vector_type(4))) float f32x4;

__device__ __forceinline__ float lrelu(float v){ return v >= 0.f ? v : SLOPE*v; }

// bf16 helpers
__device__ __forceinline__ unsigned bf_rne(float f){
    unsigned u = __float_as_uint(f);
    return (u + 0x7fffu + ((u >> 16) & 1u)) >> 16;
}
__device__ __forceinline__ unsigned pk2(float a, float b){
    return bf_rne(a) | (bf_rne(b) << 16);
}
__device__ __forceinline__ float bf_lo(unsigned u){ return __uint_as_float(u << 16); }
__device__ __forceinline__ float bf_hi(unsigned u){ return __uint_as_float(u & 0xffff0000u); }

// ---------------------------------------------------------------------------
// k_prep: parts (relP/timP) + W-pack ONLY.  (round-5 form, ~12 µs)
// ---------------------------------------------------------------------------
__global__ __launch_bounds__(256) void k_prep(
        const float* __restrict__ rel_table, const float* __restrict__ time_table,
        const float* __restrict__ W_rt, const float* __restrict__ W_fc,
        float* __restrict__ relP, float* __restrict__ timP,
        unsigned short* __restrict__ Wpk13, unsigned short* __restrict__ Wpk2)
{
    int b = blockIdx.x;
    if (b < 298) {
        int row = b*2 + (threadIdx.x >> 7);
        int j   = threadIdx.x & 127;
        if (row >= NUM_REL + NUM_TS) return;
        const float* tbl; const float* Wb; float* out;
        if (row < NUM_REL) { tbl = rel_table + row*HID;            Wb = W_rt;          out = relP + row*D; }
        else               { tbl = time_table + (row-NUM_REL)*HID; Wb = W_rt + HID*D;  out = timP + (row-NUM_REL)*D; }
        float acc = 0.f;
        #pragma unroll
        for (int k = 0; k < HID; ++k) acc += tbl[k] * Wb[k*D + j];
        out[j] = acc;
    } else {
        int id = (b - 298)*256 + threadIdx.x;   // 0..6143
        if (id < 4096) {                 // W13 frags
            int mt = id >> 8;            // 0..15
            int s  = (id >> 6) & 3;
            int l  = id & 63;
            int m  = mt*16 + (l & 15);   // output col 0..255
            int kb = s*32 + (l >> 4)*8;
            unsigned short* dst = Wpk13 + ((size_t)(mt*4 + s)*64 + l)*8;
            #pragma unroll
            for (int j = 0; j < 8; ++j) {
                int k = kb + j;
                float v = (m < D) ? W_fc[(size_t)k*D + m]
                                  : W_fc[(size_t)(256 + k)*D + (m - D)];
                dst[j] = (unsigned short)bf_rne(v);
            }
        } else {                         // W2 frags
            int id2 = id - 4096;
            int mt = id2 >> 8;           // 0..7
            int s  = (id2 >> 6) & 3;
            int l  = id2 & 63;
            int m  = mt*16 + (l & 15);
            int kb = s*32 + (l >> 4)*8;
            unsigned short* dst = Wpk2 + ((size_t)(mt*4 + s)*64 + l)*8;
            #pragma unroll
            for (int j = 0; j < 8; ++j) {
                int k = kb + j;
                dst[j] = (unsigned short)bf_rne(W_fc[(size_t)(D + k)*D + m]);
            }
        }
    }
}

// ---------------------------------------------------------------------------
// k_mm — r11 structure + ONE fix: Cs padded to XPAD stride (272 B/row).
// r11 counters: write-coalescing via Cs was real (55 -> 50.4) but the
// unpadded Cs write (node stride 256 B = bank 0 mod 32) was a 16-way LDS
// bank conflict: SQ_LDS_BANK_CONFLICT 804K -> 6.53M (~9 µs/CU-serialized).
// With stride 272 B the write's bank stride is 4 -> 2-way = free (m136);
// the coalesced 1KB global stores are unchanged (read Cs at nodeL*272+off).
// ---------------------------------------------------------------------------
__device__ __forceinline__ void xw_body(
        int xb, const float* __restrict__ x,
        const unsigned short* __restrict__ Wpk13,
        unsigned short* __restrict__ xW13bf, int n_nodes,
        unsigned short* Xs /* 64*XPAD */, unsigned short* Cs /* 64*XPAD */)
{
    int t = threadIdx.x;
    int nodeBase = xb*64;
    {   // stage X tile (fp32 -> bf16), 4 threads per node row
        int row = t >> 2;
        int k0  = (t & 3)*32;
        int node = nodeBase + row;
        unsigned short* dst = Xs + row*XPAD + k0;
        if (node < n_nodes) {
            const float4* src = (const float4*)(x + (size_t)node*D + k0);
            #pragma unroll
            for (int g = 0; g < 8; ++g) {
                float4 v = src[g];
                *(uint2*)(dst + g*4) = make_uint2(pk2(v.x, v.y), pk2(v.z, v.w));
            }
        } else {
            #pragma unroll
            for (int g = 0; g < 8; ++g)
                *(uint2*)(dst + g*4) = make_uint2(0u, 0u);
        }
    }
    __syncthreads();

    int w = t >> 6, l = t & 63;
    int li = l & 15, q = l >> 4;

    #pragma unroll 1            // halves sequential (acc reuse, reg economy)
    for (int h = 0; h < 2; ++h) {
        f32x4 acc[2][4];
        #pragma unroll
        for (int mi = 0; mi < 2; ++mi)
            #pragma unroll
            for (int ni = 0; ni < 4; ++ni) acc[mi][ni] = (f32x4){0.f,0.f,0.f,0.f};

        #pragma unroll 1
        for (int s = 0; s < 4; ++s) {
            short8 af[2], bf[4];
            #pragma unroll
            for (int mi = 0; mi < 2; ++mi) {
                int mt = w*4 + h*2 + mi;
                af[mi] = *(const short8*)(Wpk13 + ((size_t)(mt*4 + s)*64 + l)*8);
            }
            #pragma unroll
            for (int ni = 0; ni < 4; ++ni)
                bf[ni] = *(const short8*)(Xs + (ni*16 + li)*XPAD + s*32 + q*8);
            #pragma unroll
            for (int mi = 0; mi < 2; ++mi)
                #pragma unroll
                for (int ni = 0; ni < 4; ++ni)
                    acc[mi][ni] = __builtin_amdgcn_mfma_f32_16x16x32_bf16(
                                      af[mi], bf[ni], acc[mi][ni], 0, 0, 0);
        }
        // acc -> Cs (padded stride: 2-way banks, free)
        #pragma unroll
        for (int ni = 0; ni < 4; ++ni)
            #pragma unroll
            for (int mi = 0; mi < 2; ++mi) {
                int node = ni*16 + li;
                int cl   = w*32 + mi*16 + q*4;
                *(uint2*)(Cs + node*XPAD + cl) =
                    make_uint2(pk2(acc[mi][ni][0], acc[mi][ni][1]),
                               pk2(acc[mi][ni][2], acc[mi][ni][3]));
            }
        __syncthreads();
        // coalesced store: per instr, 64 lanes x 16B lane-contiguous = 1KB.
        // logical tile byte index 'flat' -> Cs byte addr nodeL*272 + off.
        // global col = (off>>6)*128 + h*64 + (off&63)  (off in bytes)
        #pragma unroll
        for (int k = 0; k < 4; ++k) {
            int flat  = (k*4 + w)*1024 + l*16;
            int nodeL = flat >> 8;
            int off   = flat & 255;
            int node  = nodeBase + nodeL;
            if (node < n_nodes) {
                uint4 v = *(const uint4*)((const char*)Cs + nodeL*(XPAD*2) + off);
                *(uint4*)((char*)(xW13bf + (size_t)node*256)
                          + (off >> 6)*128 + h*64 + (off & 63)) = v;
            }
        }
        __syncthreads();   // Cs reads done before next half rewrites it
    }
}

__device__ __forceinline__ void t2_body(
        int tb, const float* __restrict__ relP, const float* __restrict__ timP,
        const float* __restrict__ b_rt, const unsigned short* __restrict__ Wpk2,
        unsigned short* __restrict__ T2bf,
        unsigned short* Hs /* 64*XPAD */, unsigned short* Cs /* 64*XPAD */)
{
    int t = threadIdx.x;
    int cBase = tb*64;
    {   // stage H tile: lrelu(relP+timP+b) -> bf16, 4 threads per row
        int r  = t >> 2;
        int hk = (t & 3)*32;
        int combo = cBase + r;
        if (combo >= NCOMB) combo = NCOMB - 1;
        int rr = combo / NUM_TS;
        int tt = combo - rr*NUM_TS;
        const float4* rv4 = (const float4*)(relP + (size_t)rr*D + hk);
        const float4* tv4 = (const float4*)(timP + (size_t)tt*D + hk);
        const float4* bv4 = (const float4*)(b_rt + hk);
        unsigned short* dst = Hs + r*XPAD + hk;
        #pragma unroll
        for (int g = 0; g < 8; ++g) {
            float4 rv = rv4[g], tv = tv4[g], bv = bv4[g];
            float v0 = lrelu(rv.x+tv.x+bv.x), v1 = lrelu(rv.y+tv.y+bv.y);
            float v2 = lrelu(rv.z+tv.z+bv.z), v3 = lrelu(rv.w+tv.w+bv.w);
            *(uint2*)(dst + g*4) = make_uint2(pk2(v0,v1), pk2(v2,v3));
        }
    }
    __syncthreads();

    int w = t >> 6, l = t & 63;
    int li = l & 15, q = l >> 4;

    f32x4 acc[2][4];
    #pragma unroll
    for (int mi = 0; mi < 2; ++mi)
        #pragma unroll
        for (int ni = 0; ni < 4; ++ni) acc[mi][ni] = (f32x4){0.f,0.f,0.f,0.f};

    #pragma unroll 1
    for (int s = 0; s < 4; ++s) {
        short8 af[2], bf[4];
        #pragma unroll
        for (int mi = 0; mi < 2; ++mi) {
            int mt = w*2 + mi;
            af[mi] = *(const short8*)(Wpk2 + ((size_t)(mt*4 + s)*64 + l)*8);
        }
        #pragma unroll
        for (int ni = 0; ni < 4; ++ni)
            bf[ni] = *(const short8*)(Hs + (ni*16 + li)*XPAD + s*32 + q*8);
        #pragma unroll
        for (int mi = 0; mi < 2; ++mi)
            #pragma unroll
            for (int ni = 0; ni < 4; ++ni)
                acc[mi][ni] = __builtin_amdgcn_mfma_f32_16x16x32_bf16(
                                  af[mi], bf[ni], acc[mi][ni], 0, 0, 0);
    }
    // acc -> Cs (padded stride: 2-way banks, free)
    #pragma unroll
    for (int ni = 0; ni < 4; ++ni)
        #pragma unroll
        for (int mi = 0; mi < 2; ++mi) {
            int comboL = ni*16 + li;
            int cl     = (w*2 + mi)*16 + q*4;
            *(uint2*)(Cs + comboL*XPAD + cl) =
                make_uint2(pk2(acc[mi][ni][0], acc[mi][ni][1]),
                           pk2(acc[mi][ni][2], acc[mi][ni][3]));
        }
    __syncthreads();
    // coalesced store: T2bf rows are 256B contiguous -> perfect 1KB/instr
    #pragma unroll
    for (int k = 0; k < 4; ++k) {
        int flat = (k*4 + w)*1024 + l*16;
        int cL   = flat >> 8;
        int off  = flat & 255;
        int combo = cBase + cL;
        if (combo < NCOMB) {
            uint4 v = *(const uint4*)((const char*)Cs + cL*(XPAD*2) + off);
            *(uint4*)((char*)(T2bf + (size_t)combo*D) + off) = v;
        }
    }
}

__global__ __launch_bounds__(256, 3) void k_mm(
        const float* __restrict__ x, const unsigned short* __restrict__ Wpk13,
        unsigned short* __restrict__ xW13bf, int n_nodes,
        const float* __restrict__ relP, const float* __restrict__ timP,
        const float* __restrict__ b_rt, const unsigned short* __restrict__ Wpk2,
        unsigned short* __restrict__ T2bf,
        const int* __restrict__ edges, int n_edges,
        int* __restrict__ deg, int2* __restrict__ ebuf,
        int nsc, int nxw, int ntot)
{
    __shared__ __align__(16) unsigned short Hs[64*XPAD];  // 17.4 KB
    __shared__ __align__(16) unsigned short Cs[64*XPAD];  // 17.4 KB
    int b = blockIdx.x;
    // Bresenham interleave: scatter block iff cumulative count increments.
    int cumCur  = (int)(((long long)b       * nsc) / ntot);
    int cumNext = (int)(((long long)(b + 1) * nsc) / ntot);
    if (cumNext > cumCur) {
        // edge bucket-scatter (hides under co-resident MFMA blocks:
        // +12 µs vs +30 standalone). deg zeroed by hipMemsetAsync blit
        // (round-3 lesson: plain-store zeroing -> stale atomics).
        int e = cumCur*256 + threadIdx.x;
        if (e < n_edges) {
            int4 ed = ((const int4*)edges)[e];
            int slot = atomicAdd(&deg[ed.y], 1);
            if (slot < MAXDEG)   // safety clamp; statistically never taken
                ebuf[(size_t)ed.y*MAXDEG + slot] = make_int2(ed.x, ed.z*NUM_TS + ed.w);
        }
    } else {
        int cidx = b - cumNext;
        if (cidx < nxw) {
            xw_body(cidx, x, Wpk13, xW13bf, n_nodes, Hs, Cs);
        } else {
            t2_body(cidx - nxw, relP, timP, b_rt, Wpk2, T2bf, Hs, Cs);
        }
    }
}

// ---------------------------------------------------------------------------
// k_agg: 4 nodes per wave, 16 lanes per node, uint4 (16B) gathers.
// (unchanged — at the random-gather floor for this access pattern)
// ---------------------------------------------------------------------------
__global__ __launch_bounds__(256) void k_agg(
        const int* __restrict__ deg, const int2* __restrict__ ebuf,
        const unsigned short* __restrict__ xW13bf,
        const unsigned short* __restrict__ T2bf,
        const float* __restrict__ b_fc,
        float* __restrict__ out, int n_nodes)
{
    int t    = threadIdx.x;
    int lane = t & 63;
    int g    = lane >> 4;             // node group within wave (0..3)
    int sub  = lane & 15;             // lane within group; covers cols sub*8..+7
    int node = blockIdx.x*16 + (t >> 6)*4 + g;
    bool valid = node < n_nodes;
    int nodeC  = valid ? node : n_nodes - 1;

    int dg  = deg[nodeC];
    int cnt = valid ? (dg < MAXDEG ? dg : MAXDEG) : 0;
    int cm1 = cnt > 0 ? cnt - 1 : 0;
    const int2* eb = ebuf + (size_t)nodeC * MAXDEG;

    // wave-max trip count (cnt is uniform within each 16-lane group)
    int cmax = cnt;
    cmax = max(cmax, __shfl_xor(cmax, 16));
    cmax = max(cmax, __shfl_xor(cmax, 32));

    // base = xW3[node] + b_fc for this lane's 8 cols
    float base[8];
    {
        uint4  w3  = *(const uint4*)&xW13bf[(size_t)nodeC*256 + 128 + sub*8];
        float4 blo = *(const float4*)&b_fc[sub*8];
        float4 bhi = *(const float4*)&b_fc[sub*8 + 4];
        base[0] = bf_lo(w3.x) + blo.x; base[1] = bf_hi(w3.x) + blo.y;
        base[2] = bf_lo(w3.y) + blo.z; base[3] = bf_hi(w3.y) + blo.w;
        base[4] = bf_lo(w3.z) + bhi.x; base[5] = bf_hi(w3.z) + bhi.y;
        base[6] = bf_lo(w3.w) + bhi.z; base[7] = bf_hi(w3.w) + bhi.w;
    }

    float acc[8];
    #pragma unroll
    for (int k = 0; k < 8; ++k) acc[k] = 0.f;

    const unsigned sMax = (unsigned)(n_nodes - 1);
    const unsigned cMax = (unsigned)(NCOMB - 1);

    for (int e = 0; e < cmax; e += 4) {
        // --- batch 1: index loads (independent, clamped in-bounds) ---
        int2 e0 = eb[min(e + 0, cm1)];
        int2 e1 = eb[min(e + 1, cm1)];
        int2 e2 = eb[min(e + 2, cm1)];
        int2 e3 = eb[min(e + 3, cm1)];
        // --- clamp gather targets (garbage-safe for masked slots) ---
        unsigned s0 = min((unsigned)e0.x, sMax), c0 = min((unsigned)e0.y, cMax);
        unsigned s1 = min((unsigned)e1.x, sMax), c1 = min((unsigned)e1.y, cMax);
        unsigned s2 = min((unsigned)e2.x, sMax), c2 = min((unsigned)e2.y, cMax);
        unsigned s3 = min((unsigned)e3.x, sMax), c3 = min((unsigned)e3.y, cMax);
        // --- batch 2: 8 independent 16B gathers ---
        uint4 S0 = *(const uint4*)&xW13bf[(size_t)s0*256 + sub*8];
        uint4 T0 = *(const uint4*)&T2bf  [(size_t)c0*D   + sub*8];
        uint4 S1 = *(const uint4*)&xW13bf[(size_t)s1*256 + sub*8];
        uint4 T1 = *(const uint4*)&T2bf  [(size_t)c1*D   + sub*8];
        uint4 S2 = *(const uint4*)&xW13bf[(size_t)s2*256 + sub*8];
        uint4 T2 = *(const uint4*)&T2bf  [(size_t)c2*D   + sub*8];
        uint4 S3 = *(const uint4*)&xW13bf[(size_t)s3*256 + sub*8];
        uint4 T3 = *(const uint4*)&T2bf  [(size_t)c3*D   + sub*8];
        // --- consume (cndmask-masked; no divergent control flow) ---
        bool m0 = (e + 0) < cnt, m1 = (e + 1) < cnt;
        bool m2 = (e + 2) < cnt, m3 = (e + 3) < cnt;
        #pragma unroll
        for (int w = 0; w < 4; ++w) {
            unsigned Sw0 = (&S0.x)[w], Tw0 = (&T0.x)[w];
            unsigned Sw1 = (&S1.x)[w], Tw1 = (&T1.x)[w];
            unsigned Sw2 = (&S2.x)[w], Tw2 = (&T2.x)[w];
            unsigned Sw3 = (&S3.x)[w], Tw3 = (&T3.x)[w];
            float v0l = lrelu(bf_lo(Sw0) + bf_lo(Tw0) + base[2*w]);
            float v0h = lrelu(bf_hi(Sw0) + bf_hi(Tw0) + base[2*w+1]);
            float v1l = lrelu(bf_lo(Sw1) + bf_lo(Tw1) + base[2*w]);
            float v1h = lrelu(bf_hi(Sw1) + bf_hi(Tw1) + base[2*w+1]);
            float v2l = lrelu(bf_lo(Sw2) + bf_lo(Tw2) + base[2*w]);
            float v2h = lrelu(bf_hi(Sw2) + bf_hi(Tw2) + base[2*w+1]);
            float v3l = lrelu(bf_lo(Sw3) + bf_lo(Tw3) + base[2*w]);
            float v3h = lrelu(bf_hi(Sw3) + bf_hi(Tw3) + base[2*w+1]);
            float a01l = (m0 ? v0l : 0.f) + (m1 ? v1l : 0.f);
            float a23l = (m2 ? v2l : 0.f) + (m3 ? v3l : 0.f);
            float a01h = (m0 ? v0h : 0.f) + (m1 ? v1h : 0.f);
            float a23h = (m2 ? v2h : 0.f) + (m3 ? v3h : 0.f);
            acc[2*w]   += a01l + a23l;
            acc[2*w+1] += a01h + a23h;
        }
    }

    if (!valid) return;
    float inv = 1.f / fmaxf((float)dg, 1.f);
    float4 o0 = make_float4(acc[0]*inv, acc[1]*inv, acc[2]*inv, acc[3]*inv);
    float4 o1 = make_float4(acc[4]*inv, acc[5]*inv, acc[6]*inv, acc[7]*inv);
    *(float4*)&out[(size_t)node*D + sub*8]     = o0;
    *(float4*)&out[(size_t)node*D + sub*8 + 4] = o1;
}

// ---------------------------------------------------------------------------
extern "C" void kernel_launch(void* const* d_in, const int* in_sizes, int n_in,
                              void* d_out, int out_size, void* d_ws, size_t ws_size,
                              hipStream_t stream)
{
    const float* x          = (const float*)d_in[0];
    const float* rel_table  = (const float*)d_in[1];
    const float* time_table = (const float*)d_in[2];
    const float* W_rt       = (const float*)d_in[3];
    const float* b_rt       = (const float*)d_in[4];
    const float* W_fc       = (const float*)d_in[5];
    const float* b_fc       = (const float*)d_in[6];
    const int*   edges      = (const int*)d_in[7];

    int n_nodes = in_sizes[0] / D;   // 50000
    int n_edges = in_sizes[7] / 4;   // 400000
    int nsc     = (n_edges + 255) / 256;   // 1563 scatter blocks (1 e/thr, r5)
    int nxw     = (n_nodes + 63) / 64;     // 782
    int nt2     = (NCOMB + 63) / 64;       // 1312
    int ntot    = nsc + nxw + nt2;         // 3657

    char* ws = (char*)d_ws;
    size_t off = 0;
    auto alloc = [&](size_t bytes) -> void* {
        void* p = ws + off; off += (bytes + 255) & ~(size_t)255; return p;
    };
    unsigned short* xW13bf = (unsigned short*)alloc((size_t)n_nodes * 256 * 2); // 25.6 MB
    unsigned short* T2bf   = (unsigned short*)alloc((size_t)NCOMB * D * 2);     // 21.5 MB
    unsigned short* Wpk13  = (unsigned short*)alloc((size_t)16*4*64*8 * 2);     // 64 KB
    unsigned short* Wpk2   = (unsigned short*)alloc((size_t)8*4*64*8 * 2);      // 32 KB
    float* relP   = (float*)alloc((size_t)NUM_REL * D * sizeof(float));
    float* timP   = (float*)alloc((size_t)NUM_TS * D * sizeof(float));
    int*   deg    = (int*)alloc((size_t)n_nodes * sizeof(int));
    int2*  ebuf   = (int2*)alloc((size_t)n_nodes * MAXDEG * sizeof(int2));      // 25.6 MB
    if (off > ws_size)
        fprintf(stderr, "kernel_launch: workspace too small: need %zu, have %zu\n", off, ws_size);

    hipMemsetAsync(deg, 0, (size_t)n_nodes * sizeof(int), stream);

    k_prep<<<322, 256, 0, stream>>>(rel_table, time_table, W_rt, W_fc,
                                    relP, timP, Wpk13, Wpk2);
    k_mm  <<<ntot, 256, 0, stream>>>(x, Wpk13, xW13bf, n_nodes,
                                     relP, timP, b_rt, Wpk2, T2bf,
                                     edges, n_edges, deg, ebuf,
                                     nsc, nxw, ntot);
    k_agg <<<(n_nodes + 15)/16, 256, 0, stream>>>(deg, ebuf, xW13bf, T2bf,
                                                  b_fc, (float*)d_out, n_nodes);
}